// Round 4
// baseline (807.302 us; speedup 1.0000x reference)
//
#include <hip/hip_runtime.h>
#include <math.h>

#define NN 50000
#define NE 400000

typedef __attribute__((ext_vector_type(8))) short bf16x8;
typedef __attribute__((ext_vector_type(4))) float f32x4;
#define AS1 __attribute__((address_space(1)))
#define AS3 __attribute__((address_space(3)))

__device__ __forceinline__ float lrelu(float x){ return x > 0.0f ? x : 0.01f*x; }
__device__ __forceinline__ float eluf(float x){ return x > 0.0f ? x : __expf(x)-1.0f; }
__device__ __forceinline__ float bf2f(unsigned short u){
  union{unsigned i; float f;} v; v.i = ((unsigned)u)<<16; return v.f;
}
__device__ __forceinline__ unsigned short f2bf(float x){
  union{float f; unsigned i;} v; v.f = x;
  unsigned r = v.i + 0x7FFFu + ((v.i>>16)&1u);
  return (unsigned short)(r>>16);
}
__device__ __forceinline__ unsigned pack2(float a, float b){
  return (unsigned)f2bf(a) | ((unsigned)f2bf(b)<<16);
}

// ---------------- diagnostic ----------------
__global__ void k_diag(float* out, float val){ out[0] = val; }

// ---------------- fp32 -> bf16 convert ----------------
__global__ void k_cvt(const float* __restrict__ in, unsigned short* __restrict__ o, int n){
  int i = (blockIdx.x*256 + threadIdx.x)*4;
  if(i + 3 < n){
    float4 v = *(const float4*)(in + i);
    uint2 p; p.x = pack2(v.x, v.y); p.y = pack2(v.z, v.w);
    *(uint2*)(o + i) = p;
  } else {
    for(int k = i; k < n; k++) o[k] = f2bf(in[k]);
  }
}

// ---------------- fold: fl[h,d] = sum_k al[h,k]*W[h,k,d] ----------------
__global__ void k_fold(const float* __restrict__ W, const float* __restrict__ al,
    const float* __restrict__ ar, float* __restrict__ fl, float* __restrict__ fr, int K){
  int h = blockIdx.x, d = threadIdx.x;
  float sl = 0.f, sr = 0.f;
  const float* wb = W + ((size_t)h*K)*256 + d;
  for(int k = 0; k < K; k++){
    float w = wb[(size_t)k*256];
    sl += al[h*K + k]*w;
    sr += ar[h*K + k]*w;
  }
  fl[h*256 + d] = sl;
  fr[h*256 + d] = sr;
}

// ---------------- CSR build ----------------
__global__ void k_count(const int* __restrict__ dst, int* __restrict__ cnt, int E){
  int e = blockIdx.x * 256 + threadIdx.x;
  if(e < E) atomicAdd(&cnt[dst[e]], 1);
}

__global__ void k_scan(const int* __restrict__ cnt, int* __restrict__ row_ptr, int N){
  __shared__ int sums[256];
  int t = threadIdx.x;
  int per = (N + 255) >> 8;
  int s0 = t * per;
  int s1 = min(s0 + per, N);
  int s = 0;
  for(int i = s0; i < s1; ++i) s += cnt[i];
  sums[t] = s;
  __syncthreads();
  for(int off = 1; off < 256; off <<= 1){
    int u = (t >= off) ? sums[t - off] : 0;
    __syncthreads();
    sums[t] += u;
    __syncthreads();
  }
  int run = sums[t] - s;
  for(int i = s0; i < s1; ++i){ row_ptr[i] = run; run += cnt[i]; }
  if(t == 255) row_ptr[N] = sums[255];
}

__global__ void k_scatter(const int* __restrict__ src, const int* __restrict__ dst,
    const int* __restrict__ row_ptr, int* __restrict__ cur, int* __restrict__ col_src, int E){
  int e = blockIdx.x * 256 + threadIdx.x;
  if(e < E){
    int d = dst[e];
    int pos = row_ptr[d] + atomicAdd(&cur[d], 1);
    col_src[pos] = src[e];
  }
}

// ---------------- bf16 MFMA GEMM (128x128 tile, BK=32, 4 waves of 64x64) ----------------
__global__ __launch_bounds__(256) void k_gemm16(const unsigned short* __restrict__ X,
    const unsigned short* __restrict__ W, unsigned short* __restrict__ out,
    int N, int Kout, int ostride){
  __shared__ unsigned short sA[4096];
  __shared__ unsigned short sB[4096];
  int tid = threadIdx.x;
  int l = tid & 63, w = tid >> 6;
  int wm = w >> 1, wn = w & 1;
  int row0 = blockIdx.x*128, col0 = blockIdx.y*128;

  f32x4 acc[4][4];
  #pragma unroll
  for(int i=0;i<4;i++)
    #pragma unroll
    for(int j=0;j<4;j++) acc[i][j] = (f32x4){0.f,0.f,0.f,0.f};

  int grA0 = row0 + l;        if(grA0 >= N) grA0 = 0;
  int grA1 = row0 + 64 + l;   if(grA1 >= N) grA1 = 0;
  int gcB0 = col0 + l;        if(gcB0 >= Kout) gcB0 = 0;
  int gcB1 = col0 + 64 + l;   if(gcB1 >= Kout) gcB1 = 0;
  const unsigned short* pa0 = X + (size_t)grA0*256 + w*8;
  const unsigned short* pa1 = X + (size_t)grA1*256 + w*8;
  const unsigned short* pb0 = W + (size_t)gcB0*256 + w*8;
  const unsigned short* pb1 = W + (size_t)gcB1*256 + w*8;

  AS3 unsigned short* a3A = (AS3 unsigned short*)sA;
  AS3 unsigned short* a3B = (AS3 unsigned short*)sB;

  for(int kt = 0; kt < 256; kt += 32){
    __builtin_amdgcn_global_load_lds((const AS1 void*)(pa0 + kt), (AS3 void*)(a3A + w*1024),       16, 0, 0);
    __builtin_amdgcn_global_load_lds((const AS1 void*)(pa1 + kt), (AS3 void*)(a3A + w*1024 + 512), 16, 0, 0);
    __builtin_amdgcn_global_load_lds((const AS1 void*)(pb0 + kt), (AS3 void*)(a3B + w*1024),       16, 0, 0);
    __builtin_amdgcn_global_load_lds((const AS1 void*)(pb1 + kt), (AS3 void*)(a3B + w*1024 + 512), 16, 0, 0);
    __syncthreads();
    bf16x8 af[4], bfr[4];
    #pragma unroll
    for(int f=0; f<4; f++){
      af[f]  = *(const bf16x8*)(sA + (l>>4)*1024 + (wm*64 + f*16 + (l&15))*8);
      bfr[f] = *(const bf16x8*)(sB + (l>>4)*1024 + (wn*64 + f*16 + (l&15))*8);
    }
    #pragma unroll
    for(int i=0;i<4;i++)
      #pragma unroll
      for(int j=0;j<4;j++)
        acc[i][j] = __builtin_amdgcn_mfma_f32_16x16x32_bf16(af[i], bfr[j], acc[i][j], 0, 0, 0);
    __syncthreads();
  }

  #pragma unroll
  for(int i=0;i<4;i++){
    int rbase = row0 + wm*64 + i*16 + (l>>4)*4;
    #pragma unroll
    for(int j=0;j<4;j++){
      int c = col0 + wn*64 + j*16 + (l&15);
      if(c < Kout){
        #pragma unroll
        for(int q=0;q<4;q++){
          int r = rbase + q;
          if(r < N) out[(size_t)r*ostride + c] = f2bf(acc[i][j][q]);
        }
      }
    }
  }
}

// ---------------- fused final GEMM: out[n,c] = (1/6) sum_h elu(aggX_h.Wf_h^T + x.Rf_h^T) ----------------
__global__ __launch_bounds__(256) void k_gemmF(const unsigned short* __restrict__ aggX,
    const unsigned short* __restrict__ xin, const unsigned short* __restrict__ wf,
    const unsigned short* __restrict__ rf, float* __restrict__ outp, int M){
  __shared__ unsigned short sA[4096];
  __shared__ unsigned short sB[4096];
  int tid = threadIdx.x;
  int l = tid & 63, w = tid >> 6;
  int wm = w >> 1, wn = w & 1;
  int row0 = blockIdx.x*128;
  int rA0 = row0 + l;      if(rA0 >= M) rA0 = 0;
  int rA1 = row0 + 64 + l; if(rA1 >= M) rA1 = 0;
  int cB1 = 64 + l; if(cB1 > 120) cB1 = 120;

  AS3 unsigned short* a3A = (AS3 unsigned short*)sA;
  AS3 unsigned short* a3B = (AS3 unsigned short*)sB;

  f32x4 sum[4][4];
  #pragma unroll
  for(int i=0;i<4;i++)
    #pragma unroll
    for(int j=0;j<4;j++) sum[i][j] = (f32x4){0.f,0.f,0.f,0.f};

  for(int h = 0; h < 6; h++){
    f32x4 acc[4][4];
    #pragma unroll
    for(int i=0;i<4;i++)
      #pragma unroll
      for(int j=0;j<4;j++) acc[i][j] = (f32x4){0.f,0.f,0.f,0.f};

    #pragma unroll 1
    for(int ph = 0; ph < 2; ph++){
      const unsigned short* pa0 = (ph ? xin + (size_t)rA0*256 : aggX + (size_t)rA0*1536 + h*256) + w*8;
      const unsigned short* pa1 = (ph ? xin + (size_t)rA1*256 : aggX + (size_t)rA1*1536 + h*256) + w*8;
      const unsigned short* pbb = (ph ? rf : wf) + (size_t)h*121*256;
      const unsigned short* pb0 = pbb + (size_t)l*256 + w*8;
      const unsigned short* pb1 = pbb + (size_t)cB1*256 + w*8;
      for(int kt = 0; kt < 256; kt += 32){
        __builtin_amdgcn_global_load_lds((const AS1 void*)(pa0 + kt), (AS3 void*)(a3A + w*1024),       16, 0, 0);
        __builtin_amdgcn_global_load_lds((const AS1 void*)(pa1 + kt), (AS3 void*)(a3A + w*1024 + 512), 16, 0, 0);
        __builtin_amdgcn_global_load_lds((const AS1 void*)(pb0 + kt), (AS3 void*)(a3B + w*1024),       16, 0, 0);
        __builtin_amdgcn_global_load_lds((const AS1 void*)(pb1 + kt), (AS3 void*)(a3B + w*1024 + 512), 16, 0, 0);
        __syncthreads();
        bf16x8 af[4], bfr[4];
        #pragma unroll
        for(int f=0; f<4; f++){
          af[f]  = *(const bf16x8*)(sA + (l>>4)*1024 + (wm*64 + f*16 + (l&15))*8);
          bfr[f] = *(const bf16x8*)(sB + (l>>4)*1024 + (wn*64 + f*16 + (l&15))*8);
        }
        #pragma unroll
        for(int i=0;i<4;i++)
          #pragma unroll
          for(int j=0;j<4;j++)
            acc[i][j] = __builtin_amdgcn_mfma_f32_16x16x32_bf16(af[i], bfr[j], acc[i][j], 0, 0, 0);
        __syncthreads();
      }
    }
    #pragma unroll
    for(int i=0;i<4;i++)
      #pragma unroll
      for(int j=0;j<4;j++)
        #pragma unroll
        for(int q=0;q<4;q++) sum[i][j][q] += eluf(acc[i][j][q]);
  }

  const float inv6 = 1.0f/6.0f;
  #pragma unroll
  for(int i=0;i<4;i++){
    int rbase = row0 + wm*64 + i*16 + (l>>4)*4;
    #pragma unroll
    for(int j=0;j<4;j++){
      int c = wn*64 + j*16 + (l&15);
      if(c < 121){
        #pragma unroll
        for(int q=0;q<4;q++){
          int r = rbase + q;
          if(r < M) outp[(size_t)r*121 + c] = sum[i][j][q]*inv6;
        }
      }
    }
  }
}

// ---------------- folded attention scalars: a1 = x . fl[h], a2 = x . fr[h] ----------------
template<int H, int OS>
__global__ __launch_bounds__(256) void k_a12dot(const unsigned short* __restrict__ x,
    const float* __restrict__ fl, const float* __restrict__ fr,
    float* __restrict__ a1, float* __restrict__ a2){
  int n = blockIdx.x*4 + (threadIdx.x>>6);
  if(n >= NN) return;
  int l = threadIdx.x & 63;
  uint2 rv = *(const uint2*)(x + (size_t)n*256 + l*4);
  float c0 = bf2f((unsigned short)(rv.x & 0xffffu));
  float c1 = bf2f((unsigned short)(rv.x >> 16));
  float c2 = bf2f((unsigned short)(rv.y & 0xffffu));
  float c3 = bf2f((unsigned short)(rv.y >> 16));
  float s1[H], s2[H];
  #pragma unroll
  for(int h = 0; h < H; h++){
    float4 vl = *(const float4*)(fl + h*256 + l*4);
    float4 vr = *(const float4*)(fr + h*256 + l*4);
    s1[h] = c0*vl.x + c1*vl.y + c2*vl.z + c3*vl.w;
    s2[h] = c0*vr.x + c1*vr.y + c2*vr.z + c3*vr.w;
  }
  #pragma unroll
  for(int off = 32; off > 0; off >>= 1){
    #pragma unroll
    for(int h = 0; h < H; h++){
      s1[h] += __shfl_xor(s1[h], off);
      s2[h] += __shfl_xor(s2[h], off);
    }
  }
  if(l == 0){
    #pragma unroll
    for(int h = 0; h < H; h++){ a1[(size_t)n*OS + h] = s1[h]; a2[(size_t)n*OS + h] = s2[h]; }
  }
}

// ---------------- aggregation H=4 K=64 (ft messages) ----------------
template<bool HAS_RES>
__global__ __launch_bounds__(256) void k_agg4(const unsigned short* __restrict__ ft,
    const float* __restrict__ a1, const float* __restrict__ a2,
    const int* __restrict__ row_ptr, const int* __restrict__ col_src,
    const unsigned short* __restrict__ res, unsigned short* __restrict__ outp){
  int n = blockIdx.x*4 + (threadIdx.x>>6);
  if(n >= NN) return;
  int l = threadIdx.x & 63;
  int h = l >> 4;
  int e0 = row_ptr[n], e1 = row_ptr[n+1];
  float a1v = a1[n*4 + h];
  float acc0=0.f, acc1=0.f, acc2=0.f, acc3=0.f, d=0.f;
  for(int e = e0; e < e1; ++e){
    int s = col_src[e];
    float4 a2v = *(const float4*)(a2 + (size_t)s*4);
    float sc = (h==0) ? a2v.x : (h==1) ? a2v.y : (h==2) ? a2v.z : a2v.w;
    float x = __expf(lrelu(a1v + sc));
    d += x;
    uint2 rv = *(const uint2*)(ft + (size_t)s*256 + l*4);
    acc0 += x * bf2f((unsigned short)(rv.x & 0xffffu));
    acc1 += x * bf2f((unsigned short)(rv.x >> 16));
    acc2 += x * bf2f((unsigned short)(rv.y & 0xffffu));
    acc3 += x * bf2f((unsigned short)(rv.y >> 16));
  }
  float inv = (e1 > e0) ? 1.0f/d : 0.0f;
  float v0 = acc0*inv, v1 = acc1*inv, v2 = acc2*inv, v3 = acc3*inv;
  if(HAS_RES){
    uint2 rr = *(const uint2*)(res + (size_t)n*256 + l*4);
    v0 += bf2f((unsigned short)(rr.x & 0xffffu));
    v1 += bf2f((unsigned short)(rr.x >> 16));
    v2 += bf2f((unsigned short)(rr.y & 0xffffu));
    v3 += bf2f((unsigned short)(rr.y >> 16));
  }
  uint2 o;
  o.x = pack2(eluf(v0), eluf(v1));
  o.y = pack2(eluf(v2), eluf(v3));
  *(uint2*)(outp + (size_t)n*256 + l*4) = o;
}

// ---------------- final aggregation of x: aggX[n,h,:] = (sum ex*x[src])/denom ----------------
__global__ __launch_bounds__(256) void k_aggx6(const unsigned short* __restrict__ x,
    const float* __restrict__ a1, const float* __restrict__ a2,
    const int* __restrict__ row_ptr, const int* __restrict__ col_src,
    unsigned short* __restrict__ aggX, int n0base, int M){
  int idx = blockIdx.x*4 + (threadIdx.x>>6);
  if(idx >= M) return;
  int n = n0base + idx;
  int l = threadIdx.x & 63;
  int e0 = row_ptr[n], e1 = row_ptr[n+1];
  float a1v[6];
  #pragma unroll
  for(int h=0;h<6;h++) a1v[h] = a1[(size_t)n*8 + h];
  float acc[6][4];
  float d[6];
  #pragma unroll
  for(int h=0;h<6;h++){ d[h]=0.f; acc[h][0]=0.f; acc[h][1]=0.f; acc[h][2]=0.f; acc[h][3]=0.f; }
  for(int e = e0; e < e1; ++e){
    int s = col_src[e];
    const float* ap = a2 + (size_t)s*8;
    float4 alo = *(const float4*)ap;
    float2 ahi = *(const float2*)(ap + 4);
    float ex[6];
    ex[0] = __expf(lrelu(a1v[0] + alo.x));
    ex[1] = __expf(lrelu(a1v[1] + alo.y));
    ex[2] = __expf(lrelu(a1v[2] + alo.z));
    ex[3] = __expf(lrelu(a1v[3] + alo.w));
    ex[4] = __expf(lrelu(a1v[4] + ahi.x));
    ex[5] = __expf(lrelu(a1v[5] + ahi.y));
    uint2 rv = *(const uint2*)(x + (size_t)s*256 + l*4);
    float c0 = bf2f((unsigned short)(rv.x & 0xffffu));
    float c1 = bf2f((unsigned short)(rv.x >> 16));
    float c2 = bf2f((unsigned short)(rv.y & 0xffffu));
    float c3 = bf2f((unsigned short)(rv.y >> 16));
    #pragma unroll
    for(int h=0;h<6;h++){
      d[h] += ex[h];
      acc[h][0] += ex[h]*c0;
      acc[h][1] += ex[h]*c1;
      acc[h][2] += ex[h]*c2;
      acc[h][3] += ex[h]*c3;
    }
  }
  bool deg = e1 > e0;
  #pragma unroll
  for(int h=0;h<6;h++){
    float inv = deg ? 1.0f/d[h] : 0.0f;
    uint2 o;
    o.x = pack2(acc[h][0]*inv, acc[h][1]*inv);
    o.y = pack2(acc[h][2]*inv, acc[h][3]*inv);
    *(uint2*)(aggX + (size_t)idx*1536 + h*256 + l*4) = o;
  }
}

// ---------------- host ----------------
extern "C" void kernel_launch(void* const* d_in, const int* in_sizes, int n_in,
                              void* d_out, int out_size, void* d_ws, size_t ws_size,
                              hipStream_t stream){
  const float* features = (const float*)d_in[0];
  const int*   src      = (const int*)d_in[1];
  const int*   dst      = (const int*)d_in[2];
  const float* W0  = (const float*)d_in[3];
  const float* al0 = (const float*)d_in[4];
  const float* ar0 = (const float*)d_in[5];
  const float* W1  = (const float*)d_in[6];
  const float* al1 = (const float*)d_in[7];
  const float* ar1 = (const float*)d_in[8];
  const float* R1  = (const float*)d_in[9];
  const float* Wf  = (const float*)d_in[10];
  const float* alf = (const float*)d_in[11];
  const float* arf = (const float*)d_in[12];
  const float* Rf  = (const float*)d_in[13];
  float* out = (float*)d_out;
  (void)in_sizes; (void)n_in; (void)out_size;

  char* ws = (char*)d_ws;
  size_t off = 0;
  auto take = [&](size_t bytes) -> void* {
    void* p = ws + off;
    off += (bytes + 255) & ~(size_t)255;
    return p;
  };
  const int CH = 25000;
  int* row_ptr = (int*)take((NN + 1) * sizeof(int));
  int* cur     = (int*)take(NN * sizeof(int));
  int* col_src = (int*)take(NE * sizeof(int));
  float* a1 = (float*)take((size_t)NN * 8 * sizeof(float));
  float* a2 = (float*)take((size_t)NN * 8 * sizeof(float));
  unsigned short* ftbuf  = (unsigned short*)take((size_t)NN * 256 * 2);
  unsigned short* resbuf = (unsigned short*)take((size_t)NN * 256 * 2);
  unsigned short* feat16 = (unsigned short*)take((size_t)NN * 256 * 2);
  unsigned short* hA16   = (unsigned short*)take((size_t)NN * 256 * 2);
  unsigned short* hB16   = (unsigned short*)take((size_t)NN * 256 * 2);
  unsigned short* aggX   = (unsigned short*)take((size_t)CH * 1536 * 2);
  unsigned short* w016 = (unsigned short*)take(65536 * 2);
  unsigned short* w116 = (unsigned short*)take(65536 * 2);
  unsigned short* r116 = (unsigned short*)take(65536 * 2);
  unsigned short* wf16 = (unsigned short*)take(185856 * 2);
  unsigned short* rf16 = (unsigned short*)take(185856 * 2);
  float* fl0 = (float*)take(4*256*sizeof(float));
  float* fr0 = (float*)take(4*256*sizeof(float));
  float* fl1 = (float*)take(4*256*sizeof(float));
  float* fr1 = (float*)take(4*256*sizeof(float));
  float* flF = (float*)take(6*256*sizeof(float));
  float* frF = (float*)take(6*256*sizeof(float));
  size_t need = off;

  if(ws_size < need){
    k_diag<<<1, 1, 0, stream>>>(out, 100.0f + (float)((double)ws_size / 1073741824.0));
    return;
  }

  // CSR build (by dst)
  hipMemsetAsync(cur, 0, NN * sizeof(int), stream);
  k_count<<<(NE + 255)/256, 256, 0, stream>>>(dst, cur, NE);
  k_scan<<<1, 256, 0, stream>>>(cur, row_ptr, NN);
  hipMemsetAsync(cur, 0, NN * sizeof(int), stream);
  k_scatter<<<(NE + 255)/256, 256, 0, stream>>>(src, dst, row_ptr, cur, col_src, NE);

  // converts + folds
  k_cvt<<<(NN*256/4 + 255)/256, 256, 0, stream>>>(features, feat16, NN*256);
  k_cvt<<<(65536/4 + 255)/256, 256, 0, stream>>>(W0, w016, 65536);
  k_cvt<<<(65536/4 + 255)/256, 256, 0, stream>>>(W1, w116, 65536);
  k_cvt<<<(65536/4 + 255)/256, 256, 0, stream>>>(R1, r116, 65536);
  k_cvt<<<(185856/4 + 255)/256, 256, 0, stream>>>(Wf, wf16, 185856);
  k_cvt<<<(185856/4 + 255)/256, 256, 0, stream>>>(Rf, rf16, 185856);
  k_fold<<<4, 256, 0, stream>>>(W0, al0, ar0, fl0, fr0, 64);
  k_fold<<<4, 256, 0, stream>>>(W1, al1, ar1, fl1, fr1, 64);
  k_fold<<<6, 256, 0, stream>>>(Wf, alf, arf, flF, frF, 121);

  int gm = (NN + 127) / 128;   // 391
  int gagg = (NN + 3) / 4;     // 12500

  // Layer 0
  k_a12dot<4,4><<<gagg, 256, 0, stream>>>(feat16, fl0, fr0, a1, a2);
  k_gemm16<<<dim3(gm, 2), 256, 0, stream>>>(feat16, w016, ftbuf, NN, 256, 256);
  k_agg4<false><<<gagg, 256, 0, stream>>>(ftbuf, a1, a2, row_ptr, col_src, nullptr, hA16);

  // Layer 1
  k_a12dot<4,4><<<gagg, 256, 0, stream>>>(hA16, fl1, fr1, a1, a2);
  k_gemm16<<<dim3(gm, 2), 256, 0, stream>>>(hA16, w116, ftbuf, NN, 256, 256);
  k_gemm16<<<dim3(gm, 2), 256, 0, stream>>>(hA16, r116, resbuf, NN, 256, 256);
  k_agg4<true><<<gagg, 256, 0, stream>>>(ftbuf, a1, a2, row_ptr, col_src, resbuf, hB16);

  // Final layer: fold -> aggregate x -> fused per-head GEMM + elu-mean epilogue
  k_a12dot<6,8><<<gagg, 256, 0, stream>>>(hB16, flF, frF, a1, a2);
  for(int c = 0; c < 2; c++){
    int n0 = c*CH;
    k_aggx6<<<(CH + 3)/4, 256, 0, stream>>>(hB16, a1, a2, row_ptr, col_src, aggX, n0, CH);
    k_gemmF<<<(CH + 127)/128, 256, 0, stream>>>(aggX, hB16 + (size_t)n0*256, wf16, rf16,
                                                out + (size_t)n0*121, CH);
  }
}

// Round 5
// 694.772 us; speedup vs baseline: 1.1620x; 1.1620x over previous
//
#include <hip/hip_runtime.h>
#include <math.h>

#define NN 50000
#define NE 400000

typedef __attribute__((ext_vector_type(8))) short bf16x8;
typedef __attribute__((ext_vector_type(4))) float f32x4;
#define AS1 __attribute__((address_space(1)))
#define AS3 __attribute__((address_space(3)))

__device__ __forceinline__ float lrelu(float x){ return x > 0.0f ? x : 0.01f*x; }
__device__ __forceinline__ float eluf(float x){ return x > 0.0f ? x : __expf(x)-1.0f; }
__device__ __forceinline__ float bf2f(unsigned short u){
  union{unsigned i; float f;} v; v.i = ((unsigned)u)<<16; return v.f;
}
__device__ __forceinline__ unsigned short f2bf(float x){
  union{float f; unsigned i;} v; v.f = x;
  unsigned r = v.i + 0x7FFFu + ((v.i>>16)&1u);
  return (unsigned short)(r>>16);
}
__device__ __forceinline__ unsigned pack2(float a, float b){
  return (unsigned)f2bf(a) | ((unsigned)f2bf(b)<<16);
}
__device__ __forceinline__ float lo16(unsigned u){ return bf2f((unsigned short)(u & 0xffffu)); }
__device__ __forceinline__ float hi16(unsigned u){ return bf2f((unsigned short)(u >> 16)); }

// ---------------- diagnostic ----------------
__global__ void k_diag(float* out, float val){ out[0] = val; }

// ---------------- fp32 -> bf16 convert ----------------
__global__ void k_cvt(const float* __restrict__ in, unsigned short* __restrict__ o, int n){
  int i = (blockIdx.x*256 + threadIdx.x)*4;
  if(i + 3 < n){
    float4 v = *(const float4*)(in + i);
    uint2 p; p.x = pack2(v.x, v.y); p.y = pack2(v.z, v.w);
    *(uint2*)(o + i) = p;
  } else {
    for(int k = i; k < n; k++) o[k] = f2bf(in[k]);
  }
}

// ---------------- fold: fl[h,d] = sum_k al[h,k]*W[h,k,d] ----------------
__global__ void k_fold(const float* __restrict__ W, const float* __restrict__ al,
    const float* __restrict__ ar, float* __restrict__ fl, float* __restrict__ fr, int K){
  int h = blockIdx.x, d = threadIdx.x;
  float sl = 0.f, sr = 0.f;
  const float* wb = W + ((size_t)h*K)*256 + d;
  for(int k = 0; k < K; k++){
    float w = wb[(size_t)k*256];
    sl += al[h*K + k]*w;
    sr += ar[h*K + k]*w;
  }
  fl[h*256 + d] = sl;
  fr[h*256 + d] = sr;
}

// ---------------- CSR build ----------------
__global__ void k_count(const int* __restrict__ dst, int* __restrict__ cnt, int E){
  int e = blockIdx.x * 256 + threadIdx.x;
  if(e < E) atomicAdd(&cnt[dst[e]], 1);
}

__global__ void k_scan(const int* __restrict__ cnt, int* __restrict__ row_ptr, int N){
  __shared__ int sums[256];
  int t = threadIdx.x;
  int per = (N + 255) >> 8;
  int s0 = t * per;
  int s1 = min(s0 + per, N);
  int s = 0;
  for(int i = s0; i < s1; ++i) s += cnt[i];
  sums[t] = s;
  __syncthreads();
  for(int off = 1; off < 256; off <<= 1){
    int u = (t >= off) ? sums[t - off] : 0;
    __syncthreads();
    sums[t] += u;
    __syncthreads();
  }
  int run = sums[t] - s;
  for(int i = s0; i < s1; ++i){ row_ptr[i] = run; run += cnt[i]; }
  if(t == 255) row_ptr[N] = sums[255];
}

__global__ void k_scatter(const int* __restrict__ src, const int* __restrict__ dst,
    const int* __restrict__ row_ptr, int* __restrict__ cur, int* __restrict__ col_src, int E){
  int e = blockIdx.x * 256 + threadIdx.x;
  if(e < E){
    int d = dst[e];
    int pos = row_ptr[d] + atomicAdd(&cur[d], 1);
    col_src[pos] = src[e];
  }
}

// ---------------- bf16 MFMA GEMM (128x128 tile, BK=32, 4 waves of 64x64) ----------------
__global__ __launch_bounds__(256) void k_gemm16(const unsigned short* __restrict__ X,
    const unsigned short* __restrict__ W, unsigned short* __restrict__ out,
    int N, int Kout, int ostride){
  __shared__ unsigned short sA[4096];
  __shared__ unsigned short sB[4096];
  int tid = threadIdx.x;
  int l = tid & 63, w = tid >> 6;
  int wm = w >> 1, wn = w & 1;
  int row0 = blockIdx.x*128, col0 = blockIdx.y*128;

  f32x4 acc[4][4];
  #pragma unroll
  for(int i=0;i<4;i++)
    #pragma unroll
    for(int j=0;j<4;j++) acc[i][j] = (f32x4){0.f,0.f,0.f,0.f};

  int grA0 = row0 + l;        if(grA0 >= N) grA0 = 0;
  int grA1 = row0 + 64 + l;   if(grA1 >= N) grA1 = 0;
  int gcB0 = col0 + l;        if(gcB0 >= Kout) gcB0 = 0;
  int gcB1 = col0 + 64 + l;   if(gcB1 >= Kout) gcB1 = 0;
  const unsigned short* pa0 = X + (size_t)grA0*256 + w*8;
  const unsigned short* pa1 = X + (size_t)grA1*256 + w*8;
  const unsigned short* pb0 = W + (size_t)gcB0*256 + w*8;
  const unsigned short* pb1 = W + (size_t)gcB1*256 + w*8;

  AS3 unsigned short* a3A = (AS3 unsigned short*)sA;
  AS3 unsigned short* a3B = (AS3 unsigned short*)sB;

  for(int kt = 0; kt < 256; kt += 32){
    __builtin_amdgcn_global_load_lds((const AS1 void*)(pa0 + kt), (AS3 void*)(a3A + w*1024),       16, 0, 0);
    __builtin_amdgcn_global_load_lds((const AS1 void*)(pa1 + kt), (AS3 void*)(a3A + w*1024 + 512), 16, 0, 0);
    __builtin_amdgcn_global_load_lds((const AS1 void*)(pb0 + kt), (AS3 void*)(a3B + w*1024),       16, 0, 0);
    __builtin_amdgcn_global_load_lds((const AS1 void*)(pb1 + kt), (AS3 void*)(a3B + w*1024 + 512), 16, 0, 0);
    __syncthreads();
    bf16x8 af[4], bfr[4];
    #pragma unroll
    for(int f=0; f<4; f++){
      af[f]  = *(const bf16x8*)(sA + (l>>4)*1024 + (wm*64 + f*16 + (l&15))*8);
      bfr[f] = *(const bf16x8*)(sB + (l>>4)*1024 + (wn*64 + f*16 + (l&15))*8);
    }
    #pragma unroll
    for(int i=0;i<4;i++)
      #pragma unroll
      for(int j=0;j<4;j++)
        acc[i][j] = __builtin_amdgcn_mfma_f32_16x16x32_bf16(af[i], bfr[j], acc[i][j], 0, 0, 0);
    __syncthreads();
  }

  #pragma unroll
  for(int i=0;i<4;i++){
    int rbase = row0 + wm*64 + i*16 + (l>>4)*4;
    #pragma unroll
    for(int j=0;j<4;j++){
      int c = col0 + wn*64 + j*16 + (l&15);
      if(c < Kout){
        #pragma unroll
        for(int q=0;q<4;q++){
          int r = rbase + q;
          if(r < N) out[(size_t)r*ostride + c] = f2bf(acc[i][j][q]);
        }
      }
    }
  }
}

// ---------------- final GEMM, one head per block: partial[h][r][c] = elu(aggX_h.Wf_h^T + x.Rf_h^T)
__global__ __launch_bounds__(256) void k_gemmFh(const unsigned short* __restrict__ aggX,
    const unsigned short* __restrict__ xin, const unsigned short* __restrict__ wf,
    const unsigned short* __restrict__ rf, float* __restrict__ partial, int M){
  __shared__ unsigned short sA[4096];
  __shared__ unsigned short sB[4096];
  int tid = threadIdx.x;
  int l = tid & 63, w = tid >> 6;
  int wm = w >> 1, wn = w & 1;
  int h = blockIdx.y;
  int row0 = blockIdx.x*128;
  int rA0 = row0 + l;      if(rA0 >= M) rA0 = 0;
  int rA1 = row0 + 64 + l; if(rA1 >= M) rA1 = 0;
  int cB1 = 64 + l; if(cB1 > 120) cB1 = 120;

  AS3 unsigned short* a3A = (AS3 unsigned short*)sA;
  AS3 unsigned short* a3B = (AS3 unsigned short*)sB;

  f32x4 acc[4][4];
  #pragma unroll
  for(int i=0;i<4;i++)
    #pragma unroll
    for(int j=0;j<4;j++) acc[i][j] = (f32x4){0.f,0.f,0.f,0.f};

  #pragma unroll 1
  for(int ph = 0; ph < 2; ph++){
    const unsigned short* pa0 = (ph ? xin + (size_t)rA0*256 : aggX + (size_t)rA0*1536 + h*256) + w*8;
    const unsigned short* pa1 = (ph ? xin + (size_t)rA1*256 : aggX + (size_t)rA1*1536 + h*256) + w*8;
    const unsigned short* pbb = (ph ? rf : wf) + (size_t)h*121*256;
    const unsigned short* pb0 = pbb + (size_t)l*256 + w*8;
    const unsigned short* pb1 = pbb + (size_t)cB1*256 + w*8;
    for(int kt = 0; kt < 256; kt += 32){
      __builtin_amdgcn_global_load_lds((const AS1 void*)(pa0 + kt), (AS3 void*)(a3A + w*1024),       16, 0, 0);
      __builtin_amdgcn_global_load_lds((const AS1 void*)(pa1 + kt), (AS3 void*)(a3A + w*1024 + 512), 16, 0, 0);
      __builtin_amdgcn_global_load_lds((const AS1 void*)(pb0 + kt), (AS3 void*)(a3B + w*1024),       16, 0, 0);
      __builtin_amdgcn_global_load_lds((const AS1 void*)(pb1 + kt), (AS3 void*)(a3B + w*1024 + 512), 16, 0, 0);
      __syncthreads();
      bf16x8 af[4], bfr[4];
      #pragma unroll
      for(int f=0; f<4; f++){
        af[f]  = *(const bf16x8*)(sA + (l>>4)*1024 + (wm*64 + f*16 + (l&15))*8);
        bfr[f] = *(const bf16x8*)(sB + (l>>4)*1024 + (wn*64 + f*16 + (l&15))*8);
      }
      #pragma unroll
      for(int i=0;i<4;i++)
        #pragma unroll
        for(int j=0;j<4;j++)
          acc[i][j] = __builtin_amdgcn_mfma_f32_16x16x32_bf16(af[i], bfr[j], acc[i][j], 0, 0, 0);
      __syncthreads();
    }
  }

  float* pb = partial + (size_t)h*M*128;
  #pragma unroll
  for(int i=0;i<4;i++){
    int rbase = row0 + wm*64 + i*16 + (l>>4)*4;
    #pragma unroll
    for(int j=0;j<4;j++){
      int c = wn*64 + j*16 + (l&15);
      #pragma unroll
      for(int q=0;q<4;q++){
        int r = rbase + q;
        if(r < M) pb[(size_t)r*128 + c] = eluf(acc[i][j][q]);
      }
    }
  }
}

// ---------------- reduce 6 head partials -> out ----------------
__global__ __launch_bounds__(256) void k_reduce6(const float* __restrict__ partial,
    float* __restrict__ outp, int n0, int M){
  int t = blockIdx.x*256 + threadIdx.x;
  int idx = t >> 7, c = t & 127;
  if(idx >= M || c >= 121) return;
  float s = 0.f;
  #pragma unroll
  for(int h = 0; h < 6; h++) s += partial[((size_t)h*M + idx)*128 + c];
  outp[(size_t)(n0 + idx)*121 + c] = s * (1.0f/6.0f);
}

// ---------------- folded attention scalars: a1 = x . fl[h], a2 = x . fr[h] ----------------
template<int H, int OS>
__global__ __launch_bounds__(256) void k_a12dot(const unsigned short* __restrict__ x,
    const float* __restrict__ fl, const float* __restrict__ fr,
    float* __restrict__ a1, float* __restrict__ a2){
  int n = blockIdx.x*4 + (threadIdx.x>>6);
  if(n >= NN) return;
  int l = threadIdx.x & 63;
  uint2 rv = *(const uint2*)(x + (size_t)n*256 + l*4);
  float c0 = lo16(rv.x), c1 = hi16(rv.x), c2 = lo16(rv.y), c3 = hi16(rv.y);
  float s1[H], s2[H];
  #pragma unroll
  for(int h = 0; h < H; h++){
    float4 vl = *(const float4*)(fl + h*256 + l*4);
    float4 vr = *(const float4*)(fr + h*256 + l*4);
    s1[h] = c0*vl.x + c1*vl.y + c2*vl.z + c3*vl.w;
    s2[h] = c0*vr.x + c1*vr.y + c2*vr.z + c3*vr.w;
  }
  #pragma unroll
  for(int off = 32; off > 0; off >>= 1){
    #pragma unroll
    for(int h = 0; h < H; h++){
      s1[h] += __shfl_xor(s1[h], off);
      s2[h] += __shfl_xor(s2[h], off);
    }
  }
  if(l == 0){
    #pragma unroll
    for(int h = 0; h < H; h++){ a1[(size_t)n*OS + h] = s1[h]; a2[(size_t)n*OS + h] = s2[h]; }
  }
}

// ---------------- aggregation H=4 K=64, edge loop unrolled x4 ----------------
template<bool HAS_RES>
__global__ __launch_bounds__(256) void k_agg4(const unsigned short* __restrict__ ft, int fts,
    const float* __restrict__ a1, const float* __restrict__ a2,
    const int* __restrict__ row_ptr, const int* __restrict__ col_src,
    const unsigned short* __restrict__ res, int rs, unsigned short* __restrict__ outp){
  int n = blockIdx.x*4 + (threadIdx.x>>6);
  if(n >= NN) return;
  int l = threadIdx.x & 63;
  int h = l >> 4;
  int e0 = row_ptr[n], e1 = row_ptr[n+1];
  float a1v = a1[n*4 + h];
  float acc0=0.f, acc1=0.f, acc2=0.f, acc3=0.f, d=0.f;
  int e = e0;
  for(; e + 4 <= e1; e += 4){
    int s0 = col_src[e], s1 = col_src[e+1], s2 = col_src[e+2], s3 = col_src[e+3];
    float sc0 = a2[(size_t)s0*4 + h];
    float sc1 = a2[(size_t)s1*4 + h];
    float sc2 = a2[(size_t)s2*4 + h];
    float sc3 = a2[(size_t)s3*4 + h];
    uint2 r0 = *(const uint2*)(ft + (size_t)s0*fts + l*4);
    uint2 r1 = *(const uint2*)(ft + (size_t)s1*fts + l*4);
    uint2 r2 = *(const uint2*)(ft + (size_t)s2*fts + l*4);
    uint2 r3 = *(const uint2*)(ft + (size_t)s3*fts + l*4);
    float x0 = __expf(lrelu(a1v + sc0));
    float x1 = __expf(lrelu(a1v + sc1));
    float x2 = __expf(lrelu(a1v + sc2));
    float x3 = __expf(lrelu(a1v + sc3));
    d += (x0 + x1) + (x2 + x3);
    acc0 += x0*lo16(r0.x) + x1*lo16(r1.x) + x2*lo16(r2.x) + x3*lo16(r3.x);
    acc1 += x0*hi16(r0.x) + x1*hi16(r1.x) + x2*hi16(r2.x) + x3*hi16(r3.x);
    acc2 += x0*lo16(r0.y) + x1*lo16(r1.y) + x2*lo16(r2.y) + x3*lo16(r3.y);
    acc3 += x0*hi16(r0.y) + x1*hi16(r1.y) + x2*hi16(r2.y) + x3*hi16(r3.y);
  }
  for(; e < e1; ++e){
    int s = col_src[e];
    float x = __expf(lrelu(a1v + a2[(size_t)s*4 + h]));
    d += x;
    uint2 rv = *(const uint2*)(ft + (size_t)s*fts + l*4);
    acc0 += x*lo16(rv.x); acc1 += x*hi16(rv.x);
    acc2 += x*lo16(rv.y); acc3 += x*hi16(rv.y);
  }
  float inv = (e1 > e0) ? 1.0f/d : 0.0f;
  float v0 = acc0*inv, v1 = acc1*inv, v2 = acc2*inv, v3 = acc3*inv;
  if(HAS_RES){
    uint2 rr = *(const uint2*)(res + (size_t)n*rs + l*4);
    v0 += lo16(rr.x); v1 += hi16(rr.x); v2 += lo16(rr.y); v3 += hi16(rr.y);
  }
  uint2 o;
  o.x = pack2(eluf(v0), eluf(v1));
  o.y = pack2(eluf(v2), eluf(v3));
  *(uint2*)(outp + (size_t)n*256 + l*4) = o;
}

// ---------------- final aggregation of x (6 heads), edge loop unrolled x2 ----------------
__global__ __launch_bounds__(256) void k_aggx6(const unsigned short* __restrict__ x,
    const float* __restrict__ a1, const float* __restrict__ a2,
    const int* __restrict__ row_ptr, const int* __restrict__ col_src,
    unsigned short* __restrict__ aggX, int n0base, int M){
  int idx = blockIdx.x*4 + (threadIdx.x>>6);
  if(idx >= M) return;
  int n = n0base + idx;
  int l = threadIdx.x & 63;
  int e0 = row_ptr[n], e1 = row_ptr[n+1];
  float a1v[6];
  #pragma unroll
  for(int h=0;h<6;h++) a1v[h] = a1[(size_t)n*8 + h];
  float acc[6][4];
  float d[6];
  #pragma unroll
  for(int h=0;h<6;h++){ d[h]=0.f; acc[h][0]=0.f; acc[h][1]=0.f; acc[h][2]=0.f; acc[h][3]=0.f; }
  int e = e0;
  for(; e + 2 <= e1; e += 2){
    int s0 = col_src[e], s1 = col_src[e+1];
    float4 alo0 = *(const float4*)(a2 + (size_t)s0*8);
    float2 ahi0 = *(const float2*)(a2 + (size_t)s0*8 + 4);
    float4 alo1 = *(const float4*)(a2 + (size_t)s1*8);
    float2 ahi1 = *(const float2*)(a2 + (size_t)s1*8 + 4);
    uint2 rv0 = *(const uint2*)(x + (size_t)s0*256 + l*4);
    uint2 rv1 = *(const uint2*)(x + (size_t)s1*256 + l*4);
    float ex0[6], ex1[6];
    ex0[0] = __expf(lrelu(a1v[0] + alo0.x));
    ex0[1] = __expf(lrelu(a1v[1] + alo0.y));
    ex0[2] = __expf(lrelu(a1v[2] + alo0.z));
    ex0[3] = __expf(lrelu(a1v[3] + alo0.w));
    ex0[4] = __expf(lrelu(a1v[4] + ahi0.x));
    ex0[5] = __expf(lrelu(a1v[5] + ahi0.y));
    ex1[0] = __expf(lrelu(a1v[0] + alo1.x));
    ex1[1] = __expf(lrelu(a1v[1] + alo1.y));
    ex1[2] = __expf(lrelu(a1v[2] + alo1.z));
    ex1[3] = __expf(lrelu(a1v[3] + alo1.w));
    ex1[4] = __expf(lrelu(a1v[4] + ahi1.x));
    ex1[5] = __expf(lrelu(a1v[5] + ahi1.y));
    float c00 = lo16(rv0.x), c01 = hi16(rv0.x), c02 = lo16(rv0.y), c03 = hi16(rv0.y);
    float c10 = lo16(rv1.x), c11 = hi16(rv1.x), c12 = lo16(rv1.y), c13 = hi16(rv1.y);
    #pragma unroll
    for(int h=0;h<6;h++){
      d[h] += ex0[h] + ex1[h];
      acc[h][0] += ex0[h]*c00 + ex1[h]*c10;
      acc[h][1] += ex0[h]*c01 + ex1[h]*c11;
      acc[h][2] += ex0[h]*c02 + ex1[h]*c12;
      acc[h][3] += ex0[h]*c03 + ex1[h]*c13;
    }
  }
  for(; e < e1; ++e){
    int s = col_src[e];
    float4 alo = *(const float4*)(a2 + (size_t)s*8);
    float2 ahi = *(const float2*)(a2 + (size_t)s*8 + 4);
    uint2 rv = *(const uint2*)(x + (size_t)s*256 + l*4);
    float ex[6];
    ex[0] = __expf(lrelu(a1v[0] + alo.x));
    ex[1] = __expf(lrelu(a1v[1] + alo.y));
    ex[2] = __expf(lrelu(a1v[2] + alo.z));
    ex[3] = __expf(lrelu(a1v[3] + alo.w));
    ex[4] = __expf(lrelu(a1v[4] + ahi.x));
    ex[5] = __expf(lrelu(a1v[5] + ahi.y));
    float c0 = lo16(rv.x), c1 = hi16(rv.x), c2 = lo16(rv.y), c3 = hi16(rv.y);
    #pragma unroll
    for(int h=0;h<6;h++){
      d[h] += ex[h];
      acc[h][0] += ex[h]*c0;
      acc[h][1] += ex[h]*c1;
      acc[h][2] += ex[h]*c2;
      acc[h][3] += ex[h]*c3;
    }
  }
  bool deg = e1 > e0;
  #pragma unroll
  for(int h=0;h<6;h++){
    float inv = deg ? 1.0f/d[h] : 0.0f;
    uint2 o;
    o.x = pack2(acc[h][0]*inv, acc[h][1]*inv);
    o.y = pack2(acc[h][2]*inv, acc[h][3]*inv);
    *(uint2*)(aggX + (size_t)idx*1536 + h*256 + l*4) = o;
  }
}

// ---------------- host ----------------
extern "C" void kernel_launch(void* const* d_in, const int* in_sizes, int n_in,
                              void* d_out, int out_size, void* d_ws, size_t ws_size,
                              hipStream_t stream){
  const float* features = (const float*)d_in[0];
  const int*   src      = (const int*)d_in[1];
  const int*   dst      = (const int*)d_in[2];
  const float* W0  = (const float*)d_in[3];
  const float* al0 = (const float*)d_in[4];
  const float* ar0 = (const float*)d_in[5];
  const float* W1  = (const float*)d_in[6];
  const float* al1 = (const float*)d_in[7];
  const float* ar1 = (const float*)d_in[8];
  const float* R1  = (const float*)d_in[9];
  const float* Wf  = (const float*)d_in[10];
  const float* alf = (const float*)d_in[11];
  const float* arf = (const float*)d_in[12];
  const float* Rf  = (const float*)d_in[13];
  float* out = (float*)d_out;
  (void)in_sizes; (void)n_in; (void)out_size;

  char* ws = (char*)d_ws;
  size_t off = 0;
  auto take = [&](size_t bytes) -> void* {
    void* p = ws + off;
    off += (bytes + 255) & ~(size_t)255;
    return p;
  };
  const int CH = 25000;
  int* row_ptr = (int*)take((NN + 1) * sizeof(int));
  int* cur     = (int*)take(NN * sizeof(int));
  int* col_src = (int*)take(NE * sizeof(int));
  float* a1 = (float*)take((size_t)NN * 8 * sizeof(float));
  float* a2 = (float*)take((size_t)NN * 8 * sizeof(float));
  // ftres: [N,512] bf16 for layer-1 (cols 0-255 ft, 256-511 res); layer-0 uses first [N,256].
  // In the final phase this whole region (+feat16) is dead and reused as fp32 partials [6][CH][128].
  unsigned short* ftres  = (unsigned short*)take((size_t)NN * 512 * 2);  // 51.2 MB
  unsigned short* feat16 = (unsigned short*)take((size_t)NN * 256 * 2);  // 25.6 MB (contiguous after ftres)
  unsigned short* hA16   = (unsigned short*)take((size_t)NN * 256 * 2);
  unsigned short* hB16   = (unsigned short*)take((size_t)NN * 256 * 2);
  unsigned short* aggX   = (unsigned short*)take((size_t)CH * 1536 * 2); // 76.8 MB
  unsigned short* w016  = (unsigned short*)take(65536 * 2);
  unsigned short* w1r1  = (unsigned short*)take(131072 * 2);   // [W1;R1] stacked rows
  unsigned short* wf16  = (unsigned short*)take(185856 * 2);
  unsigned short* rf16  = (unsigned short*)take(185856 * 2);
  float* fl0 = (float*)take(4*256*sizeof(float));
  float* fr0 = (float*)take(4*256*sizeof(float));
  float* fl1 = (float*)take(4*256*sizeof(float));
  float* fr1 = (float*)take(4*256*sizeof(float));
  float* flF = (float*)take(6*256*sizeof(float));
  float* frF = (float*)take(6*256*sizeof(float));
  size_t need = off;

  if(ws_size < need){
    k_diag<<<1, 1, 0, stream>>>(out, 100.0f + (float)((double)ws_size / 1073741824.0));
    return;
  }

  // fp32 partials [6][CH][128] alias the dead ftres+feat16 region (76.8 MB exactly)
  float* partialF = (float*)ftres;

  // CSR build (by dst)
  hipMemsetAsync(cur, 0, NN * sizeof(int), stream);
  k_count<<<(NE + 255)/256, 256, 0, stream>>>(dst, cur, NE);
  k_scan<<<1, 256, 0, stream>>>(cur, row_ptr, NN);
  hipMemsetAsync(cur, 0, NN * sizeof(int), stream);
  k_scatter<<<(NE + 255)/256, 256, 0, stream>>>(src, dst, row_ptr, cur, col_src, NE);

  // converts + folds
  k_cvt<<<(NN*256/4 + 255)/256, 256, 0, stream>>>(features, feat16, NN*256);
  k_cvt<<<(65536/4 + 255)/256, 256, 0, stream>>>(W0, w016, 65536);
  k_cvt<<<(65536/4 + 255)/256, 256, 0, stream>>>(W1, w1r1, 65536);
  k_cvt<<<(65536/4 + 255)/256, 256, 0, stream>>>(R1, w1r1 + 65536, 65536);
  k_cvt<<<(185856/4 + 255)/256, 256, 0, stream>>>(Wf, wf16, 185856);
  k_cvt<<<(185856/4 + 255)/256, 256, 0, stream>>>(Rf, rf16, 185856);
  k_fold<<<4, 256, 0, stream>>>(W0, al0, ar0, fl0, fr0, 64);
  k_fold<<<4, 256, 0, stream>>>(W1, al1, ar1, fl1, fr1, 64);
  k_fold<<<6, 256, 0, stream>>>(Wf, alf, arf, flF, frF, 121);

  int gm = (NN + 127) / 128;   // 391
  int gagg = (NN + 3) / 4;     // 12500

  // Layer 0: ft -> ftres[:, :256] (stride 256 layout, standalone region use)
  k_a12dot<4,4><<<gagg, 256, 0, stream>>>(feat16, fl0, fr0, a1, a2);
  k_gemm16<<<dim3(gm, 2), 256, 0, stream>>>(feat16, w016, ftres, NN, 256, 256);
  k_agg4<false><<<gagg, 256, 0, stream>>>(ftres, 256, a1, a2, row_ptr, col_src, nullptr, 0, hA16);

  // Layer 1: one GEMM produces [ft | res] with stride 512
  k_a12dot<4,4><<<gagg, 256, 0, stream>>>(hA16, fl1, fr1, a1, a2);
  k_gemm16<<<dim3(gm, 4), 256, 0, stream>>>(hA16, w1r1, ftres, NN, 512, 512);
  k_agg4<true><<<gagg, 256, 0, stream>>>(ftres, 512, a1, a2, row_ptr, col_src, ftres + 256, 512, hB16);

  // Final layer: a12 -> aggregate x -> head-parallel GEMM+elu -> reduce mean
  k_a12dot<6,8><<<gagg, 256, 0, stream>>>(hB16, flF, frF, a1, a2);
  for(int c = 0; c < 2; c++){
    int n0 = c*CH;
    k_aggx6<<<(CH + 3)/4, 256, 0, stream>>>(hB16, a1, a2, row_ptr, col_src, aggX, n0, CH);
    k_gemmFh<<<dim3((CH + 127)/128, 6), 256, 0, stream>>>(aggX, hB16 + (size_t)n0*256, wf16, rf16, partialF, CH);
    k_reduce6<<<(CH*128 + 255)/256, 256, 0, stream>>>(partialF, out, n0, CH);
  }
}

// Round 6
// 605.175 us; speedup vs baseline: 1.3340x; 1.1481x over previous
//
#include <hip/hip_runtime.h>
#include <math.h>

#define NN 50000
#define NE 400000
#define NB ((NN + 255) / 256)   // 196 scan blocks

typedef __attribute__((ext_vector_type(8))) short bf16x8;
typedef __attribute__((ext_vector_type(4))) float f32x4;
#define AS1 __attribute__((address_space(1)))
#define AS3 __attribute__((address_space(3)))

__device__ __forceinline__ float lrelu(float x){ return x > 0.0f ? x : 0.01f*x; }
__device__ __forceinline__ float eluf(float x){ return x > 0.0f ? x : __expf(x)-1.0f; }
__device__ __forceinline__ float bf2f(unsigned short u){
  union{unsigned i; float f;} v; v.i = ((unsigned)u)<<16; return v.f;
}
__device__ __forceinline__ unsigned short f2bf(float x){
  union{float f; unsigned i;} v; v.f = x;
  unsigned r = v.i + 0x7FFFu + ((v.i>>16)&1u);
  return (unsigned short)(r>>16);
}
__device__ __forceinline__ unsigned pack2(float a, float b){
  return (unsigned)f2bf(a) | ((unsigned)f2bf(b)<<16);
}
__device__ __forceinline__ float lo16(unsigned u){ return bf2f((unsigned short)(u & 0xffffu)); }
__device__ __forceinline__ float hi16(unsigned u){ return bf2f((unsigned short)(u >> 16)); }

// ---------------- diagnostic ----------------
__global__ void k_diag(float* out, float val){ out[0] = val; }

// ---------------- fp32 -> bf16 convert ----------------
__global__ void k_cvt(const float* __restrict__ in, unsigned short* __restrict__ o, int n){
  int i = (blockIdx.x*256 + threadIdx.x)*4;
  if(i + 3 < n){
    float4 v = *(const float4*)(in + i);
    uint2 p; p.x = pack2(v.x, v.y); p.y = pack2(v.z, v.w);
    *(uint2*)(o + i) = p;
  } else {
    for(int k = i; k < n; k++) o[k] = f2bf(in[k]);
  }
}

// convert 3 same-size tensors (blockIdx.y selects)
__global__ void k_cvt3(const float* __restrict__ s0, const float* __restrict__ s1,
    const float* __restrict__ s2, unsigned short* __restrict__ d0,
    unsigned short* __restrict__ d1, unsigned short* __restrict__ d2, int n){
  const float* in = (blockIdx.y == 0) ? s0 : (blockIdx.y == 1) ? s1 : s2;
  unsigned short* o = (blockIdx.y == 0) ? d0 : (blockIdx.y == 1) ? d1 : d2;
  int i = (blockIdx.x*256 + threadIdx.x)*4;
  if(i + 3 < n){
    float4 v = *(const float4*)(in + i);
    uint2 p; p.x = pack2(v.x, v.y); p.y = pack2(v.z, v.w);
    *(uint2*)(o + i) = p;
  } else {
    for(int k = i; k < n; k++) o[k] = f2bf(in[k]);
  }
}

// convert 2 same-size tensors
__global__ void k_cvt2(const float* __restrict__ s0, const float* __restrict__ s1,
    unsigned short* __restrict__ d0, unsigned short* __restrict__ d1, int n){
  const float* in = (blockIdx.y == 0) ? s0 : s1;
  unsigned short* o = (blockIdx.y == 0) ? d0 : d1;
  int i = (blockIdx.x*256 + threadIdx.x)*4;
  if(i + 3 < n){
    float4 v = *(const float4*)(in + i);
    uint2 p; p.x = pack2(v.x, v.y); p.y = pack2(v.z, v.w);
    *(uint2*)(o + i) = p;
  } else {
    for(int k = i; k < n; k++) o[k] = f2bf(in[k]);
  }
}

// ---------------- fold: fl[h,d] = sum_k al[h,k]*W[h,k,d] ----------------
__global__ void k_fold(const float* __restrict__ W, const float* __restrict__ al,
    const float* __restrict__ ar, float* __restrict__ fl, float* __restrict__ fr, int K){
  int h = blockIdx.x, d = threadIdx.x;
  float sl = 0.f, sr = 0.f;
  const float* wb = W + ((size_t)h*K)*256 + d;
  for(int k = 0; k < K; k++){
    float w = wb[(size_t)k*256];
    sl += al[h*K + k]*w;
    sr += ar[h*K + k]*w;
  }
  fl[h*256 + d] = sl;
  fr[h*256 + d] = sr;
}

// ---------------- CSR build ----------------
__global__ void k_count(const int* __restrict__ dst, int* __restrict__ cnt, int E){
  int e = blockIdx.x * 256 + threadIdx.x;
  if(e < E) atomicAdd(&cnt[dst[e]], 1);
}

// hierarchical exclusive scan: A) per-block local scan + block sums
__global__ void k_scanA(const int* __restrict__ cnt, int* __restrict__ row_ptr,
    int* __restrict__ bsum, int N){
  __shared__ int sh[256];
  int t = threadIdx.x;
  int i = blockIdx.x*256 + t;
  int v = (i < N) ? cnt[i] : 0;
  sh[t] = v;
  __syncthreads();
  for(int off = 1; off < 256; off <<= 1){
    int u = (t >= off) ? sh[t - off] : 0;
    __syncthreads();
    sh[t] += u;
    __syncthreads();
  }
  if(i < N) row_ptr[i] = sh[t] - v;           // local exclusive
  if(t == 255) bsum[blockIdx.x] = sh[255];    // block total
}

// B) scan of block sums (NB <= 256)
__global__ void k_scanB(const int* __restrict__ bsum, int* __restrict__ boff, int nb){
  __shared__ int sh[256];
  int t = threadIdx.x;
  int v = (t < nb) ? bsum[t] : 0;
  sh[t] = v;
  __syncthreads();
  for(int off = 1; off < 256; off <<= 1){
    int u = (t >= off) ? sh[t - off] : 0;
    __syncthreads();
    sh[t] += u;
    __syncthreads();
  }
  if(t < nb) boff[t] = sh[t] - v;
  if(t == 255) boff[nb] = sh[255];            // grand total
}

// C) add block offsets
__global__ void k_scanC(int* __restrict__ row_ptr, const int* __restrict__ boff, int N, int nb){
  int i = blockIdx.x*256 + threadIdx.x;
  if(i < N) row_ptr[i] += boff[blockIdx.x];
  if(i == 0) row_ptr[N] = boff[nb];
}

__global__ void k_scatter(const int* __restrict__ src, const int* __restrict__ dst,
    const int* __restrict__ row_ptr, int* __restrict__ cur, int* __restrict__ col_src, int E){
  int e = blockIdx.x * 256 + threadIdx.x;
  if(e < E){
    int d = dst[e];
    int pos = row_ptr[d] + atomicAdd(&cur[d], 1);
    col_src[pos] = src[e];
  }
}

// ---------------- bf16 MFMA GEMM (128x128 tile, BK=32, 4 waves of 64x64) ----------------
__global__ __launch_bounds__(256) void k_gemm16(const unsigned short* __restrict__ X,
    const unsigned short* __restrict__ W, unsigned short* __restrict__ out,
    int N, int Kout, int ostride){
  __shared__ unsigned short sA[4096];
  __shared__ unsigned short sB[4096];
  int tid = threadIdx.x;
  int l = tid & 63, w = tid >> 6;
  int wm = w >> 1, wn = w & 1;
  int row0 = blockIdx.x*128, col0 = blockIdx.y*128;

  f32x4 acc[4][4];
  #pragma unroll
  for(int i=0;i<4;i++)
    #pragma unroll
    for(int j=0;j<4;j++) acc[i][j] = (f32x4){0.f,0.f,0.f,0.f};

  int grA0 = row0 + l;        if(grA0 >= N) grA0 = 0;
  int grA1 = row0 + 64 + l;   if(grA1 >= N) grA1 = 0;
  int gcB0 = col0 + l;        if(gcB0 >= Kout) gcB0 = 0;
  int gcB1 = col0 + 64 + l;   if(gcB1 >= Kout) gcB1 = 0;
  const unsigned short* pa0 = X + (size_t)grA0*256 + w*8;
  const unsigned short* pa1 = X + (size_t)grA1*256 + w*8;
  const unsigned short* pb0 = W + (size_t)gcB0*256 + w*8;
  const unsigned short* pb1 = W + (size_t)gcB1*256 + w*8;

  AS3 unsigned short* a3A = (AS3 unsigned short*)sA;
  AS3 unsigned short* a3B = (AS3 unsigned short*)sB;

  for(int kt = 0; kt < 256; kt += 32){
    __builtin_amdgcn_global_load_lds((const AS1 void*)(pa0 + kt), (AS3 void*)(a3A + w*1024),       16, 0, 0);
    __builtin_amdgcn_global_load_lds((const AS1 void*)(pa1 + kt), (AS3 void*)(a3A + w*1024 + 512), 16, 0, 0);
    __builtin_amdgcn_global_load_lds((const AS1 void*)(pb0 + kt), (AS3 void*)(a3B + w*1024),       16, 0, 0);
    __builtin_amdgcn_global_load_lds((const AS1 void*)(pb1 + kt), (AS3 void*)(a3B + w*1024 + 512), 16, 0, 0);
    __syncthreads();
    bf16x8 af[4], bfr[4];
    #pragma unroll
    for(int f=0; f<4; f++){
      af[f]  = *(const bf16x8*)(sA + (l>>4)*1024 + (wm*64 + f*16 + (l&15))*8);
      bfr[f] = *(const bf16x8*)(sB + (l>>4)*1024 + (wn*64 + f*16 + (l&15))*8);
    }
    #pragma unroll
    for(int i=0;i<4;i++)
      #pragma unroll
      for(int j=0;j<4;j++)
        acc[i][j] = __builtin_amdgcn_mfma_f32_16x16x32_bf16(af[i], bfr[j], acc[i][j], 0, 0, 0);
    __syncthreads();
  }

  #pragma unroll
  for(int i=0;i<4;i++){
    int rbase = row0 + wm*64 + i*16 + (l>>4)*4;
    #pragma unroll
    for(int j=0;j<4;j++){
      int c = col0 + wn*64 + j*16 + (l&15);
      if(c < Kout){
        #pragma unroll
        for(int q=0;q<4;q++){
          int r = rbase + q;
          if(r < N) out[(size_t)r*ostride + c] = f2bf(acc[i][j][q]);
        }
      }
    }
  }
}

// ---------------- final GEMM, one head per block ----------------
__global__ __launch_bounds__(256) void k_gemmFh(const unsigned short* __restrict__ aggX,
    const unsigned short* __restrict__ xin, const unsigned short* __restrict__ wf,
    const unsigned short* __restrict__ rf, float* __restrict__ partial, int M){
  __shared__ unsigned short sA[4096];
  __shared__ unsigned short sB[4096];
  int tid = threadIdx.x;
  int l = tid & 63, w = tid >> 6;
  int wm = w >> 1, wn = w & 1;
  int h = blockIdx.y;
  int row0 = blockIdx.x*128;
  int rA0 = row0 + l;      if(rA0 >= M) rA0 = 0;
  int rA1 = row0 + 64 + l; if(rA1 >= M) rA1 = 0;
  int cB1 = 64 + l; if(cB1 > 120) cB1 = 120;

  AS3 unsigned short* a3A = (AS3 unsigned short*)sA;
  AS3 unsigned short* a3B = (AS3 unsigned short*)sB;

  f32x4 acc[4][4];
  #pragma unroll
  for(int i=0;i<4;i++)
    #pragma unroll
    for(int j=0;j<4;j++) acc[i][j] = (f32x4){0.f,0.f,0.f,0.f};

  #pragma unroll 1
  for(int ph = 0; ph < 2; ph++){
    const unsigned short* pa0 = (ph ? xin + (size_t)rA0*256 : aggX + (size_t)rA0*1536 + h*256) + w*8;
    const unsigned short* pa1 = (ph ? xin + (size_t)rA1*256 : aggX + (size_t)rA1*1536 + h*256) + w*8;
    const unsigned short* pbb = (ph ? rf : wf) + (size_t)h*121*256;
    const unsigned short* pb0 = pbb + (size_t)l*256 + w*8;
    const unsigned short* pb1 = pbb + (size_t)cB1*256 + w*8;
    for(int kt = 0; kt < 256; kt += 32){
      __builtin_amdgcn_global_load_lds((const AS1 void*)(pa0 + kt), (AS3 void*)(a3A + w*1024),       16, 0, 0);
      __builtin_amdgcn_global_load_lds((const AS1 void*)(pa1 + kt), (AS3 void*)(a3A + w*1024 + 512), 16, 0, 0);
      __builtin_amdgcn_global_load_lds((const AS1 void*)(pb0 + kt), (AS3 void*)(a3B + w*1024),       16, 0, 0);
      __builtin_amdgcn_global_load_lds((const AS1 void*)(pb1 + kt), (AS3 void*)(a3B + w*1024 + 512), 16, 0, 0);
      __syncthreads();
      bf16x8 af[4], bfr[4];
      #pragma unroll
      for(int f=0; f<4; f++){
        af[f]  = *(const bf16x8*)(sA + (l>>4)*1024 + (wm*64 + f*16 + (l&15))*8);
        bfr[f] = *(const bf16x8*)(sB + (l>>4)*1024 + (wn*64 + f*16 + (l&15))*8);
      }
      #pragma unroll
      for(int i=0;i<4;i++)
        #pragma unroll
        for(int j=0;j<4;j++)
          acc[i][j] = __builtin_amdgcn_mfma_f32_16x16x32_bf16(af[i], bfr[j], acc[i][j], 0, 0, 0);
      __syncthreads();
    }
  }

  float* pb = partial + (size_t)h*M*128;
  #pragma unroll
  for(int i=0;i<4;i++){
    int rbase = row0 + wm*64 + i*16 + (l>>4)*4;
    #pragma unroll
    for(int j=0;j<4;j++){
      int c = wn*64 + j*16 + (l&15);
      #pragma unroll
      for(int q=0;q<4;q++){
        int r = rbase + q;
        if(r < M) pb[(size_t)r*128 + c] = eluf(acc[i][j][q]);
      }
    }
  }
}

// ---------------- reduce 6 head partials -> out ----------------
__global__ __launch_bounds__(256) void k_reduce6(const float* __restrict__ partial,
    float* __restrict__ outp, int n0, int M){
  int t = blockIdx.x*256 + threadIdx.x;
  int idx = t >> 7, c = t & 127;
  if(idx >= M || c >= 121) return;
  float s = 0.f;
  #pragma unroll
  for(int h = 0; h < 6; h++) s += partial[((size_t)h*M + idx)*128 + c];
  outp[(size_t)(n0 + idx)*121 + c] = s * (1.0f/6.0f);
}

// ---------------- folded attention scalars ----------------
template<int H, int OS>
__global__ __launch_bounds__(256) void k_a12dot(const unsigned short* __restrict__ x,
    const float* __restrict__ fl, const float* __restrict__ fr,
    float* __restrict__ a1, float* __restrict__ a2){
  int n = blockIdx.x*4 + (threadIdx.x>>6);
  if(n >= NN) return;
  int l = threadIdx.x & 63;
  uint2 rv = *(const uint2*)(x + (size_t)n*256 + l*4);
  float c0 = lo16(rv.x), c1 = hi16(rv.x), c2 = lo16(rv.y), c3 = hi16(rv.y);
  float s1[H], s2[H];
  #pragma unroll
  for(int h = 0; h < H; h++){
    float4 vl = *(const float4*)(fl + h*256 + l*4);
    float4 vr = *(const float4*)(fr + h*256 + l*4);
    s1[h] = c0*vl.x + c1*vl.y + c2*vl.z + c3*vl.w;
    s2[h] = c0*vr.x + c1*vr.y + c2*vr.z + c3*vr.w;
  }
  #pragma unroll
  for(int off = 32; off > 0; off >>= 1){
    #pragma unroll
    for(int h = 0; h < H; h++){
      s1[h] += __shfl_xor(s1[h], off);
      s2[h] += __shfl_xor(s2[h], off);
    }
  }
  if(l == 0){
    #pragma unroll
    for(int h = 0; h < H; h++){ a1[(size_t)n*OS + h] = s1[h]; a2[(size_t)n*OS + h] = s2[h]; }
  }
}

// ---------------- aggregation H=4 K=64, edge loop unrolled x4 ----------------
template<bool HAS_RES>
__global__ __launch_bounds__(256) void k_agg4(const unsigned short* __restrict__ ft, int fts,
    const float* __restrict__ a1, const float* __restrict__ a2,
    const int* __restrict__ row_ptr, const int* __restrict__ col_src,
    const unsigned short* __restrict__ res, int rs, unsigned short* __restrict__ outp){
  int n = blockIdx.x*4 + (threadIdx.x>>6);
  if(n >= NN) return;
  int l = threadIdx.x & 63;
  int h = l >> 4;
  int e0 = row_ptr[n], e1 = row_ptr[n+1];
  float a1v = a1[n*4 + h];
  float acc0=0.f, acc1=0.f, acc2=0.f, acc3=0.f, d=0.f;
  int e = e0;
  for(; e + 4 <= e1; e += 4){
    int s0 = col_src[e], s1 = col_src[e+1], s2 = col_src[e+2], s3 = col_src[e+3];
    float sc0 = a2[(size_t)s0*4 + h];
    float sc1 = a2[(size_t)s1*4 + h];
    float sc2 = a2[(size_t)s2*4 + h];
    float sc3 = a2[(size_t)s3*4 + h];
    uint2 r0 = *(const uint2*)(ft + (size_t)s0*fts + l*4);
    uint2 r1 = *(const uint2*)(ft + (size_t)s1*fts + l*4);
    uint2 r2 = *(const uint2*)(ft + (size_t)s2*fts + l*4);
    uint2 r3 = *(const uint2*)(ft + (size_t)s3*fts + l*4);
    float x0 = __expf(lrelu(a1v + sc0));
    float x1 = __expf(lrelu(a1v + sc1));
    float x2 = __expf(lrelu(a1v + sc2));
    float x3 = __expf(lrelu(a1v + sc3));
    d += (x0 + x1) + (x2 + x3);
    acc0 += x0*lo16(r0.x) + x1*lo16(r1.x) + x2*lo16(r2.x) + x3*lo16(r3.x);
    acc1 += x0*hi16(r0.x) + x1*hi16(r1.x) + x2*hi16(r2.x) + x3*hi16(r3.x);
    acc2 += x0*lo16(r0.y) + x1*lo16(r1.y) + x2*lo16(r2.y) + x3*lo16(r3.y);
    acc3 += x0*hi16(r0.y) + x1*hi16(r1.y) + x2*hi16(r2.y) + x3*hi16(r3.y);
  }
  for(; e < e1; ++e){
    int s = col_src[e];
    float x = __expf(lrelu(a1v + a2[(size_t)s*4 + h]));
    d += x;
    uint2 rv = *(const uint2*)(ft + (size_t)s*fts + l*4);
    acc0 += x*lo16(rv.x); acc1 += x*hi16(rv.x);
    acc2 += x*lo16(rv.y); acc3 += x*hi16(rv.y);
  }
  float inv = (e1 > e0) ? 1.0f/d : 0.0f;
  float v0 = acc0*inv, v1 = acc1*inv, v2 = acc2*inv, v3 = acc3*inv;
  if(HAS_RES){
    uint2 rr = *(const uint2*)(res + (size_t)n*rs + l*4);
    v0 += lo16(rr.x); v1 += hi16(rr.x); v2 += lo16(rr.y); v3 += hi16(rr.y);
  }
  uint2 o;
  o.x = pack2(eluf(v0), eluf(v1));
  o.y = pack2(eluf(v2), eluf(v3));
  *(uint2*)(outp + (size_t)n*256 + l*4) = o;
}

// ---------------- final aggregation of x (6 heads), edge loop unrolled x2 ----------------
__global__ __launch_bounds__(256) void k_aggx6(const unsigned short* __restrict__ x,
    const float* __restrict__ a1, const float* __restrict__ a2,
    const int* __restrict__ row_ptr, const int* __restrict__ col_src,
    unsigned short* __restrict__ aggX, int n0base, int M){
  int idx = blockIdx.x*4 + (threadIdx.x>>6);
  if(idx >= M) return;
  int n = n0base + idx;
  int l = threadIdx.x & 63;
  int e0 = row_ptr[n], e1 = row_ptr[n+1];
  float a1v[6];
  #pragma unroll
  for(int h=0;h<6;h++) a1v[h] = a1[(size_t)n*8 + h];
  float acc[6][4];
  float d[6];
  #pragma unroll
  for(int h=0;h<6;h++){ d[h]=0.f; acc[h][0]=0.f; acc[h][1]=0.f; acc[h][2]=0.f; acc[h][3]=0.f; }
  int e = e0;
  for(; e + 2 <= e1; e += 2){
    int s0 = col_src[e], s1 = col_src[e+1];
    float4 alo0 = *(const float4*)(a2 + (size_t)s0*8);
    float2 ahi0 = *(const float2*)(a2 + (size_t)s0*8 + 4);
    float4 alo1 = *(const float4*)(a2 + (size_t)s1*8);
    float2 ahi1 = *(const float2*)(a2 + (size_t)s1*8 + 4);
    uint2 rv0 = *(const uint2*)(x + (size_t)s0*256 + l*4);
    uint2 rv1 = *(const uint2*)(x + (size_t)s1*256 + l*4);
    float ex0[6], ex1[6];
    ex0[0] = __expf(lrelu(a1v[0] + alo0.x));
    ex0[1] = __expf(lrelu(a1v[1] + alo0.y));
    ex0[2] = __expf(lrelu(a1v[2] + alo0.z));
    ex0[3] = __expf(lrelu(a1v[3] + alo0.w));
    ex0[4] = __expf(lrelu(a1v[4] + ahi0.x));
    ex0[5] = __expf(lrelu(a1v[5] + ahi0.y));
    ex1[0] = __expf(lrelu(a1v[0] + alo1.x));
    ex1[1] = __expf(lrelu(a1v[1] + alo1.y));
    ex1[2] = __expf(lrelu(a1v[2] + alo1.z));
    ex1[3] = __expf(lrelu(a1v[3] + alo1.w));
    ex1[4] = __expf(lrelu(a1v[4] + ahi1.x));
    ex1[5] = __expf(lrelu(a1v[5] + ahi1.y));
    float c00 = lo16(rv0.x), c01 = hi16(rv0.x), c02 = lo16(rv0.y), c03 = hi16(rv0.y);
    float c10 = lo16(rv1.x), c11 = hi16(rv1.x), c12 = lo16(rv1.y), c13 = hi16(rv1.y);
    #pragma unroll
    for(int h=0;h<6;h++){
      d[h] += ex0[h] + ex1[h];
      acc[h][0] += ex0[h]*c00 + ex1[h]*c10;
      acc[h][1] += ex0[h]*c01 + ex1[h]*c11;
      acc[h][2] += ex0[h]*c02 + ex1[h]*c12;
      acc[h][3] += ex0[h]*c03 + ex1[h]*c13;
    }
  }
  for(; e < e1; ++e){
    int s = col_src[e];
    float4 alo = *(const float4*)(a2 + (size_t)s*8);
    float2 ahi = *(const float2*)(a2 + (size_t)s*8 + 4);
    uint2 rv = *(const uint2*)(x + (size_t)s*256 + l*4);
    float ex[6];
    ex[0] = __expf(lrelu(a1v[0] + alo.x));
    ex[1] = __expf(lrelu(a1v[1] + alo.y));
    ex[2] = __expf(lrelu(a1v[2] + alo.z));
    ex[3] = __expf(lrelu(a1v[3] + alo.w));
    ex[4] = __expf(lrelu(a1v[4] + ahi.x));
    ex[5] = __expf(lrelu(a1v[5] + ahi.y));
    float c0 = lo16(rv.x), c1 = hi16(rv.x), c2 = lo16(rv.y), c3 = hi16(rv.y);
    #pragma unroll
    for(int h=0;h<6;h++){
      d[h] += ex[h];
      acc[h][0] += ex[h]*c0;
      acc[h][1] += ex[h]*c1;
      acc[h][2] += ex[h]*c2;
      acc[h][3] += ex[h]*c3;
    }
  }
  bool deg = e1 > e0;
  #pragma unroll
  for(int h=0;h<6;h++){
    float inv = deg ? 1.0f/d[h] : 0.0f;
    uint2 o;
    o.x = pack2(acc[h][0]*inv, acc[h][1]*inv);
    o.y = pack2(acc[h][2]*inv, acc[h][3]*inv);
    *(uint2*)(aggX + (size_t)idx*1536 + h*256 + l*4) = o;
  }
}

// ---------------- host ----------------
extern "C" void kernel_launch(void* const* d_in, const int* in_sizes, int n_in,
                              void* d_out, int out_size, void* d_ws, size_t ws_size,
                              hipStream_t stream){
  const float* features = (const float*)d_in[0];
  const int*   src      = (const int*)d_in[1];
  const int*   dst      = (const int*)d_in[2];
  const float* W0  = (const float*)d_in[3];
  const float* al0 = (const float*)d_in[4];
  const float* ar0 = (const float*)d_in[5];
  const float* W1  = (const float*)d_in[6];
  const float* al1 = (const float*)d_in[7];
  const float* ar1 = (const float*)d_in[8];
  const float* R1  = (const float*)d_in[9];
  const float* Wf  = (const float*)d_in[10];
  const float* alf = (const float*)d_in[11];
  const float* arf = (const float*)d_in[12];
  const float* Rf  = (const float*)d_in[13];
  float* out = (float*)d_out;
  (void)in_sizes; (void)n_in; (void)out_size;

  char* ws = (char*)d_ws;
  size_t off = 0;
  auto take = [&](size_t bytes) -> void* {
    void* p = ws + off;
    off += (bytes + 255) & ~(size_t)255;
    return p;
  };
  const int CH = 25000;
  int* row_ptr = (int*)take((NN + 1) * sizeof(int));
  int* cur     = (int*)take(NN * sizeof(int));
  int* col_src = (int*)take(NE * sizeof(int));
  int* bsum    = (int*)take(256 * sizeof(int));
  int* boff    = (int*)take(257 * sizeof(int));
  float* a1 = (float*)take((size_t)NN * 8 * sizeof(float));
  float* a2 = (float*)take((size_t)NN * 8 * sizeof(float));
  unsigned short* ftres  = (unsigned short*)take((size_t)NN * 512 * 2);  // 51.2 MB
  unsigned short* feat16 = (unsigned short*)take((size_t)NN * 256 * 2);  // 25.6 MB
  unsigned short* hA16   = (unsigned short*)take((size_t)NN * 256 * 2);
  unsigned short* hB16   = (unsigned short*)take((size_t)NN * 256 * 2);
  unsigned short* aggX   = (unsigned short*)take((size_t)CH * 1536 * 2); // 76.8 MB
  unsigned short* w016  = (unsigned short*)take(65536 * 2);
  unsigned short* w1r1  = (unsigned short*)take(131072 * 2);
  unsigned short* wf16  = (unsigned short*)take(185856 * 2);
  unsigned short* rf16  = (unsigned short*)take(185856 * 2);
  float* fl0 = (float*)take(4*256*sizeof(float));
  float* fr0 = (float*)take(4*256*sizeof(float));
  float* fl1 = (float*)take(4*256*sizeof(float));
  float* fr1 = (float*)take(4*256*sizeof(float));
  float* flF = (float*)take(6*256*sizeof(float));
  float* frF = (float*)take(6*256*sizeof(float));
  size_t need = off;

  if(ws_size < need){
    k_diag<<<1, 1, 0, stream>>>(out, 100.0f + (float)((double)ws_size / 1073741824.0));
    return;
  }

  float* partialF = (float*)ftres;   // fp32 partials [6][CH][128] alias dead ftres+feat16

  // CSR build (by dst) with hierarchical scan
  hipMemsetAsync(cur, 0, NN * sizeof(int), stream);
  k_count<<<(NE + 255)/256, 256, 0, stream>>>(dst, cur, NE);
  k_scanA<<<NB, 256, 0, stream>>>(cur, row_ptr, bsum, NN);
  k_scanB<<<1, 256, 0, stream>>>(bsum, boff, NB);
  k_scanC<<<NB, 256, 0, stream>>>(row_ptr, boff, NN, NB);
  hipMemsetAsync(cur, 0, NN * sizeof(int), stream);
  k_scatter<<<(NE + 255)/256, 256, 0, stream>>>(src, dst, row_ptr, cur, col_src, NE);

  // converts + folds
  k_cvt<<<(NN*256/4 + 255)/256, 256, 0, stream>>>(features, feat16, NN*256);
  k_cvt3<<<dim3(64, 3), 256, 0, stream>>>(W0, W1, R1, w016, w1r1, w1r1 + 65536, 65536);
  k_cvt2<<<dim3(182, 2), 256, 0, stream>>>(Wf, Rf, wf16, rf16, 185856);
  k_fold<<<4, 256, 0, stream>>>(W0, al0, ar0, fl0, fr0, 64);
  k_fold<<<4, 256, 0, stream>>>(W1, al1, ar1, fl1, fr1, 64);
  k_fold<<<6, 256, 0, stream>>>(Wf, alf, arf, flF, frF, 121);

  int gm = (NN + 127) / 128;   // 391
  int gagg = (NN + 3) / 4;     // 12500

  // Layer 0
  k_a12dot<4,4><<<gagg, 256, 0, stream>>>(feat16, fl0, fr0, a1, a2);
  k_gemm16<<<dim3(gm, 2), 256, 0, stream>>>(feat16, w016, ftres, NN, 256, 256);
  k_agg4<false><<<gagg, 256, 0, stream>>>(ftres, 256, a1, a2, row_ptr, col_src, nullptr, 0, hA16);

  // Layer 1 (fused [W1;R1] GEMM, stride-512 output)
  k_a12dot<4,4><<<gagg, 256, 0, stream>>>(hA16, fl1, fr1, a1, a2);
  k_gemm16<<<dim3(gm, 4), 256, 0, stream>>>(hA16, w1r1, ftres, NN, 512, 512);
  k_agg4<true><<<gagg, 256, 0, stream>>>(ftres, 512, a1, a2, row_ptr, col_src, ftres + 256, 512, hB16);

  // Final layer
  k_a12dot<6,8><<<gagg, 256, 0, stream>>>(hB16, flF, frF, a1, a2);
  for(int c = 0; c < 2; c++){
    int n0 = c*CH;
    k_aggx6<<<(CH + 3)/4, 256, 0, stream>>>(hB16, a1, a2, row_ptr, col_src, aggX, n0, CH);
    k_gemmFh<<<dim3((CH + 127)/128, 6), 256, 0, stream>>>(aggX, hB16 + (size_t)n0*256, wf16, rf16, partialF, CH);
    k_reduce6<<<(CH*128 + 255)/256, 256, 0, stream>>>(partialF, out, n0, CH);
  }
}

// Round 7
// 517.665 us; speedup vs baseline: 1.5595x; 1.1690x over previous
//
#include <hip/hip_runtime.h>
#include <math.h>

#define NN 50000
#define NE 400000
#define NB ((NN + 255) / 256)   // 196 scan blocks

typedef __attribute__((ext_vector_type(8))) short bf16x8;
typedef __attribute__((ext_vector_type(4))) float f32x4;
#define AS1 __attribute__((address_space(1)))
#define AS3 __attribute__((address_space(3)))

__device__ __forceinline__ float lrelu(float x){ return x > 0.0f ? x : 0.01f*x; }
__device__ __forceinline__ float eluf(float x){ return x > 0.0f ? x : __expf(x)-1.0f; }
__device__ __forceinline__ float bf2f(unsigned short u){
  union{unsigned i; float f;} v; v.i = ((unsigned)u)<<16; return v.f;
}
__device__ __forceinline__ unsigned short f2bf(float x){
  union{float f; unsigned i;} v; v.f = x;
  unsigned r = v.i + 0x7FFFu + ((v.i>>16)&1u);
  return (unsigned short)(r>>16);
}
__device__ __forceinline__ unsigned pack2(float a, float b){
  return (unsigned)f2bf(a) | ((unsigned)f2bf(b)<<16);
}
__device__ __forceinline__ float lo16(unsigned u){ return bf2f((unsigned short)(u & 0xffffu)); }
__device__ __forceinline__ float hi16(unsigned u){ return bf2f((unsigned short)(u >> 16)); }

// ---------------- diagnostic ----------------
__global__ void k_diag(float* out, float val){ out[0] = val; }

// ---------------- fp32 -> bf16 convert ----------------
__global__ void k_cvt(const float* __restrict__ in, unsigned short* __restrict__ o, int n){
  int i = (blockIdx.x*256 + threadIdx.x)*4;
  if(i + 3 < n){
    float4 v = *(const float4*)(in + i);
    uint2 p; p.x = pack2(v.x, v.y); p.y = pack2(v.z, v.w);
    *(uint2*)(o + i) = p;
  } else {
    for(int k = i; k < n; k++) o[k] = f2bf(in[k]);
  }
}

__global__ void k_cvt3(const float* __restrict__ s0, const float* __restrict__ s1,
    const float* __restrict__ s2, unsigned short* __restrict__ d0,
    unsigned short* __restrict__ d1, unsigned short* __restrict__ d2, int n){
  const float* in = (blockIdx.y == 0) ? s0 : (blockIdx.y == 1) ? s1 : s2;
  unsigned short* o = (blockIdx.y == 0) ? d0 : (blockIdx.y == 1) ? d1 : d2;
  int i = (blockIdx.x*256 + threadIdx.x)*4;
  if(i + 3 < n){
    float4 v = *(const float4*)(in + i);
    uint2 p; p.x = pack2(v.x, v.y); p.y = pack2(v.z, v.w);
    *(uint2*)(o + i) = p;
  } else {
    for(int k = i; k < n; k++) o[k] = f2bf(in[k]);
  }
}

__global__ void k_cvt2(const float* __restrict__ s0, const float* __restrict__ s1,
    unsigned short* __restrict__ d0, unsigned short* __restrict__ d1, int n){
  const float* in = (blockIdx.y == 0) ? s0 : s1;
  unsigned short* o = (blockIdx.y == 0) ? d0 : d1;
  int i = (blockIdx.x*256 + threadIdx.x)*4;
  if(i + 3 < n){
    float4 v = *(const float4*)(in + i);
    uint2 p; p.x = pack2(v.x, v.y); p.y = pack2(v.z, v.w);
    *(uint2*)(o + i) = p;
  } else {
    for(int k = i; k < n; k++) o[k] = f2bf(in[k]);
  }
}

// ---------------- all folds in one launch: blocks 0-3 L0, 4-7 L1, 8-13 final ----------------
__global__ void k_foldAll(const float* __restrict__ W0, const float* __restrict__ al0, const float* __restrict__ ar0,
    const float* __restrict__ W1, const float* __restrict__ al1, const float* __restrict__ ar1,
    const float* __restrict__ Wf, const float* __restrict__ alf, const float* __restrict__ arf,
    float* __restrict__ fl0, float* __restrict__ fr0, float* __restrict__ fl1, float* __restrict__ fr1,
    float* __restrict__ flF, float* __restrict__ frF){
  int b = blockIdx.x, d = threadIdx.x;
  const float *W, *al, *ar; float *fl, *fr; int K, h;
  if(b < 4){ W=W0; al=al0; ar=ar0; fl=fl0; fr=fr0; K=64; h=b; }
  else if(b < 8){ W=W1; al=al1; ar=ar1; fl=fl1; fr=fr1; K=64; h=b-4; }
  else { W=Wf; al=alf; ar=arf; fl=flF; fr=frF; K=121; h=b-8; }
  float sl = 0.f, sr = 0.f;
  const float* wb = W + ((size_t)h*K)*256 + d;
  for(int k = 0; k < K; k++){
    float w = wb[(size_t)k*256];
    sl += al[h*K + k]*w;
    sr += ar[h*K + k]*w;
  }
  fl[h*256 + d] = sl;
  fr[h*256 + d] = sr;
}

// ---------------- CSR build ----------------
__global__ void k_count(const int* __restrict__ dst, int* __restrict__ cnt, int E){
  int e = blockIdx.x * 256 + threadIdx.x;
  if(e < E) atomicAdd(&cnt[dst[e]], 1);
}

__global__ void k_scanA(const int* __restrict__ cnt, int* __restrict__ row_ptr,
    int* __restrict__ bsum, int N){
  __shared__ int sh[256];
  int t = threadIdx.x;
  int i = blockIdx.x*256 + t;
  int v = (i < N) ? cnt[i] : 0;
  sh[t] = v;
  __syncthreads();
  for(int off = 1; off < 256; off <<= 1){
    int u = (t >= off) ? sh[t - off] : 0;
    __syncthreads();
    sh[t] += u;
    __syncthreads();
  }
  if(i < N) row_ptr[i] = sh[t] - v;
  if(t == 255) bsum[blockIdx.x] = sh[255];
}

__global__ void k_scanB(const int* __restrict__ bsum, int* __restrict__ boff, int nb){
  __shared__ int sh[256];
  int t = threadIdx.x;
  int v = (t < nb) ? bsum[t] : 0;
  sh[t] = v;
  __syncthreads();
  for(int off = 1; off < 256; off <<= 1){
    int u = (t >= off) ? sh[t - off] : 0;
    __syncthreads();
    sh[t] += u;
    __syncthreads();
  }
  if(t < nb) boff[t] = sh[t] - v;
  if(t == 255) boff[nb] = sh[255];
}

__global__ void k_scanC(int* __restrict__ row_ptr, const int* __restrict__ boff, int N, int nb){
  int i = blockIdx.x*256 + threadIdx.x;
  if(i < N) row_ptr[i] += boff[blockIdx.x];
  if(i == 0) row_ptr[N] = boff[nb];
}

__global__ void k_scatter(const int* __restrict__ src, const int* __restrict__ dst,
    const int* __restrict__ row_ptr, int* __restrict__ cur, int* __restrict__ col_src, int E){
  int e = blockIdx.x * 256 + threadIdx.x;
  if(e < E){
    int d = dst[e];
    int pos = row_ptr[d] + atomicAdd(&cur[d], 1);
    col_src[pos] = src[e];
  }
}

// ---------------- bf16 MFMA GEMM (128x128 tile, BK=32, 4 waves of 64x64) ----------------
__global__ __launch_bounds__(256) void k_gemm16(const unsigned short* __restrict__ X,
    const unsigned short* __restrict__ W, unsigned short* __restrict__ out,
    int N, int Kout, int ostride){
  __shared__ unsigned short sA[4096];
  __shared__ unsigned short sB[4096];
  int tid = threadIdx.x;
  int l = tid & 63, w = tid >> 6;
  int wm = w >> 1, wn = w & 1;
  int row0 = blockIdx.x*128, col0 = blockIdx.y*128;

  f32x4 acc[4][4];
  #pragma unroll
  for(int i=0;i<4;i++)
    #pragma unroll
    for(int j=0;j<4;j++) acc[i][j] = (f32x4){0.f,0.f,0.f,0.f};

  int grA0 = row0 + l;        if(grA0 >= N) grA0 = 0;
  int grA1 = row0 + 64 + l;   if(grA1 >= N) grA1 = 0;
  int gcB0 = col0 + l;        if(gcB0 >= Kout) gcB0 = 0;
  int gcB1 = col0 + 64 + l;   if(gcB1 >= Kout) gcB1 = 0;
  const unsigned short* pa0 = X + (size_t)grA0*256 + w*8;
  const unsigned short* pa1 = X + (size_t)grA1*256 + w*8;
  const unsigned short* pb0 = W + (size_t)gcB0*256 + w*8;
  const unsigned short* pb1 = W + (size_t)gcB1*256 + w*8;

  AS3 unsigned short* a3A = (AS3 unsigned short*)sA;
  AS3 unsigned short* a3B = (AS3 unsigned short*)sB;

  for(int kt = 0; kt < 256; kt += 32){
    __builtin_amdgcn_global_load_lds((const AS1 void*)(pa0 + kt), (AS3 void*)(a3A + w*1024),       16, 0, 0);
    __builtin_amdgcn_global_load_lds((const AS1 void*)(pa1 + kt), (AS3 void*)(a3A + w*1024 + 512), 16, 0, 0);
    __builtin_amdgcn_global_load_lds((const AS1 void*)(pb0 + kt), (AS3 void*)(a3B + w*1024),       16, 0, 0);
    __builtin_amdgcn_global_load_lds((const AS1 void*)(pb1 + kt), (AS3 void*)(a3B + w*1024 + 512), 16, 0, 0);
    __syncthreads();
    bf16x8 af[4], bfr[4];
    #pragma unroll
    for(int f=0; f<4; f++){
      af[f]  = *(const bf16x8*)(sA + (l>>4)*1024 + (wm*64 + f*16 + (l&15))*8);
      bfr[f] = *(const bf16x8*)(sB + (l>>4)*1024 + (wn*64 + f*16 + (l&15))*8);
    }
    #pragma unroll
    for(int i=0;i<4;i++)
      #pragma unroll
      for(int j=0;j<4;j++)
        acc[i][j] = __builtin_amdgcn_mfma_f32_16x16x32_bf16(af[i], bfr[j], acc[i][j], 0, 0, 0);
    __syncthreads();
  }

  #pragma unroll
  for(int i=0;i<4;i++){
    int rbase = row0 + wm*64 + i*16 + (l>>4)*4;
    #pragma unroll
    for(int j=0;j<4;j++){
      int c = col0 + wn*64 + j*16 + (l&15);
      if(c < Kout){
        #pragma unroll
        for(int q=0;q<4;q++){
          int r = rbase + q;
          if(r < N) out[(size_t)r*ostride + c] = f2bf(acc[i][j][q]);
        }
      }
    }
  }
}

// ---------------- final GEMM, one head per block; bf16 elu partials ----------------
__global__ __launch_bounds__(256) void k_gemmFh(const unsigned short* __restrict__ aggX,
    const unsigned short* __restrict__ xin, const unsigned short* __restrict__ wf,
    const unsigned short* __restrict__ rf, unsigned short* __restrict__ partial, int M){
  __shared__ unsigned short sA[4096];
  __shared__ unsigned short sB[4096];
  int tid = threadIdx.x;
  int l = tid & 63, w = tid >> 6;
  int wm = w >> 1, wn = w & 1;
  int h = blockIdx.y;
  int row0 = blockIdx.x*128;
  int rA0 = row0 + l;      if(rA0 >= M) rA0 = 0;
  int rA1 = row0 + 64 + l; if(rA1 >= M) rA1 = 0;
  int cB1 = 64 + l; if(cB1 > 120) cB1 = 120;

  AS3 unsigned short* a3A = (AS3 unsigned short*)sA;
  AS3 unsigned short* a3B = (AS3 unsigned short*)sB;

  f32x4 acc[4][4];
  #pragma unroll
  for(int i=0;i<4;i++)
    #pragma unroll
    for(int j=0;j<4;j++) acc[i][j] = (f32x4){0.f,0.f,0.f,0.f};

  #pragma unroll 1
  for(int ph = 0; ph < 2; ph++){
    const unsigned short* pa0 = (ph ? xin + (size_t)rA0*256 : aggX + (size_t)rA0*1536 + h*256) + w*8;
    const unsigned short* pa1 = (ph ? xin + (size_t)rA1*256 : aggX + (size_t)rA1*1536 + h*256) + w*8;
    const unsigned short* pbb = (ph ? rf : wf) + (size_t)h*121*256;
    const unsigned short* pb0 = pbb + (size_t)l*256 + w*8;
    const unsigned short* pb1 = pbb + (size_t)cB1*256 + w*8;
    for(int kt = 0; kt < 256; kt += 32){
      __builtin_amdgcn_global_load_lds((const AS1 void*)(pa0 + kt), (AS3 void*)(a3A + w*1024),       16, 0, 0);
      __builtin_amdgcn_global_load_lds((const AS1 void*)(pa1 + kt), (AS3 void*)(a3A + w*1024 + 512), 16, 0, 0);
      __builtin_amdgcn_global_load_lds((const AS1 void*)(pb0 + kt), (AS3 void*)(a3B + w*1024),       16, 0, 0);
      __builtin_amdgcn_global_load_lds((const AS1 void*)(pb1 + kt), (AS3 void*)(a3B + w*1024 + 512), 16, 0, 0);
      __syncthreads();
      bf16x8 af[4], bfr[4];
      #pragma unroll
      for(int f=0; f<4; f++){
        af[f]  = *(const bf16x8*)(sA + (l>>4)*1024 + (wm*64 + f*16 + (l&15))*8);
        bfr[f] = *(const bf16x8*)(sB + (l>>4)*1024 + (wn*64 + f*16 + (l&15))*8);
      }
      #pragma unroll
      for(int i=0;i<4;i++)
        #pragma unroll
        for(int j=0;j<4;j++)
          acc[i][j] = __builtin_amdgcn_mfma_f32_16x16x32_bf16(af[i], bfr[j], acc[i][j], 0, 0, 0);
      __syncthreads();
    }
  }

  unsigned short* pb = partial + (size_t)h*M*128;
  #pragma unroll
  for(int i=0;i<4;i++){
    int rbase = row0 + wm*64 + i*16 + (l>>4)*4;
    #pragma unroll
    for(int j=0;j<4;j++){
      int c = wn*64 + j*16 + (l&15);
      #pragma unroll
      for(int q=0;q<4;q++){
        int r = rbase + q;
        if(r < M) pb[(size_t)r*128 + c] = f2bf(eluf(acc[i][j][q]));
      }
    }
  }
}

// ---------------- reduce 6 bf16 head partials -> out ----------------
__global__ __launch_bounds__(256) void k_reduce6(const unsigned short* __restrict__ partial,
    float* __restrict__ outp, int n0, int M){
  int t = blockIdx.x*256 + threadIdx.x;
  int idx = t >> 7, c = t & 127;
  if(idx >= M || c >= 121) return;
  float s = 0.f;
  #pragma unroll
  for(int h = 0; h < 6; h++) s += bf2f(partial[((size_t)h*M + idx)*128 + c]);
  outp[(size_t)(n0 + idx)*121 + c] = s * (1.0f/6.0f);
}

// ---------------- folded attention scalars (layer 0 only) ----------------
template<int H, int OS>
__global__ __launch_bounds__(256) void k_a12dot(const unsigned short* __restrict__ x,
    const float* __restrict__ fl, const float* __restrict__ fr,
    float* __restrict__ a1, float* __restrict__ a2){
  int n = blockIdx.x*4 + (threadIdx.x>>6);
  if(n >= NN) return;
  int l = threadIdx.x & 63;
  uint2 rv = *(const uint2*)(x + (size_t)n*256 + l*4);
  float c0 = lo16(rv.x), c1 = hi16(rv.x), c2 = lo16(rv.y), c3 = hi16(rv.y);
  float s1[H], s2[H];
  #pragma unroll
  for(int h = 0; h < H; h++){
    float4 vl = *(const float4*)(fl + h*256 + l*4);
    float4 vr = *(const float4*)(fr + h*256 + l*4);
    s1[h] = c0*vl.x + c1*vl.y + c2*vl.z + c3*vl.w;
    s2[h] = c0*vr.x + c1*vr.y + c2*vr.z + c3*vr.w;
  }
  #pragma unroll
  for(int off = 32; off > 0; off >>= 1){
    #pragma unroll
    for(int h = 0; h < H; h++){
      s1[h] += __shfl_xor(s1[h], off);
      s2[h] += __shfl_xor(s2[h], off);
    }
  }
  if(l == 0){
    #pragma unroll
    for(int h = 0; h < H; h++){ a1[(size_t)n*OS + h] = s1[h]; a2[(size_t)n*OS + h] = s2[h]; }
  }
}

// ---------------- aggregation H=4 K=64, unroll x4, fused next-layer a12 epilogue ----------------
// reads a1/a2 (this layer, stride 4); writes na1/na2 (next layer, stride NOS) for NH next heads.
template<bool HAS_RES, int NH, int NOS>
__global__ __launch_bounds__(256) void k_agg4(const unsigned short* __restrict__ ft, int fts,
    const float* __restrict__ a1, const float* __restrict__ a2,
    const int* __restrict__ row_ptr, const int* __restrict__ col_src,
    const unsigned short* __restrict__ res, int rs, unsigned short* __restrict__ outp,
    const float* __restrict__ nfl, const float* __restrict__ nfr,
    float* __restrict__ na1, float* __restrict__ na2){
  int n = blockIdx.x*4 + (threadIdx.x>>6);
  if(n >= NN) return;
  int l = threadIdx.x & 63;
  int h = l >> 4;
  int e0 = row_ptr[n], e1 = row_ptr[n+1];
  float a1v = a1[n*4 + h];
  float acc0=0.f, acc1=0.f, acc2=0.f, acc3=0.f, d=0.f;
  int e = e0;
  for(; e + 4 <= e1; e += 4){
    int s0 = col_src[e], s1 = col_src[e+1], s2 = col_src[e+2], s3 = col_src[e+3];
    float sc0 = a2[(size_t)s0*4 + h];
    float sc1 = a2[(size_t)s1*4 + h];
    float sc2 = a2[(size_t)s2*4 + h];
    float sc3 = a2[(size_t)s3*4 + h];
    uint2 r0 = *(const uint2*)(ft + (size_t)s0*fts + l*4);
    uint2 r1 = *(const uint2*)(ft + (size_t)s1*fts + l*4);
    uint2 r2 = *(const uint2*)(ft + (size_t)s2*fts + l*4);
    uint2 r3 = *(const uint2*)(ft + (size_t)s3*fts + l*4);
    float x0 = __expf(lrelu(a1v + sc0));
    float x1 = __expf(lrelu(a1v + sc1));
    float x2 = __expf(lrelu(a1v + sc2));
    float x3 = __expf(lrelu(a1v + sc3));
    d += (x0 + x1) + (x2 + x3);
    acc0 += x0*lo16(r0.x) + x1*lo16(r1.x) + x2*lo16(r2.x) + x3*lo16(r3.x);
    acc1 += x0*hi16(r0.x) + x1*hi16(r1.x) + x2*hi16(r2.x) + x3*hi16(r3.x);
    acc2 += x0*lo16(r0.y) + x1*lo16(r1.y) + x2*lo16(r2.y) + x3*lo16(r3.y);
    acc3 += x0*hi16(r0.y) + x1*hi16(r1.y) + x2*hi16(r2.y) + x3*hi16(r3.y);
  }
  for(; e < e1; ++e){
    int s = col_src[e];
    float x = __expf(lrelu(a1v + a2[(size_t)s*4 + h]));
    d += x;
    uint2 rv = *(const uint2*)(ft + (size_t)s*fts + l*4);
    acc0 += x*lo16(rv.x); acc1 += x*hi16(rv.x);
    acc2 += x*lo16(rv.y); acc3 += x*hi16(rv.y);
  }
  float inv = (e1 > e0) ? 1.0f/d : 0.0f;
  float v0 = acc0*inv, v1 = acc1*inv, v2 = acc2*inv, v3 = acc3*inv;
  if(HAS_RES){
    uint2 rr = *(const uint2*)(res + (size_t)n*rs + l*4);
    v0 += lo16(rr.x); v1 += hi16(rr.x); v2 += lo16(rr.y); v3 += hi16(rr.y);
  }
  float o0 = eluf(v0), o1 = eluf(v1), o2 = eluf(v2), o3 = eluf(v3);
  uint2 o;
  o.x = pack2(o0, o1);
  o.y = pack2(o2, o3);
  *(uint2*)(outp + (size_t)n*256 + l*4) = o;

  // fused a12 for next layer
  float s1[NH], s2[NH];
  #pragma unroll
  for(int hh = 0; hh < NH; hh++){
    float4 vl = *(const float4*)(nfl + hh*256 + l*4);
    float4 vr = *(const float4*)(nfr + hh*256 + l*4);
    s1[hh] = o0*vl.x + o1*vl.y + o2*vl.z + o3*vl.w;
    s2[hh] = o0*vr.x + o1*vr.y + o2*vr.z + o3*vr.w;
  }
  #pragma unroll
  for(int off = 32; off > 0; off >>= 1){
    #pragma unroll
    for(int hh = 0; hh < NH; hh++){
      s1[hh] += __shfl_xor(s1[hh], off);
      s2[hh] += __shfl_xor(s2[hh], off);
    }
  }
  if(l == 0){
    #pragma unroll
    for(int hh = 0; hh < NH; hh++){
      na1[(size_t)n*NOS + hh] = s1[hh];
      na2[(size_t)n*NOS + hh] = s2[hh];
    }
  }
}

// ---------------- final aggregation of x (6 heads), unroll x2 ----------------
__global__ __launch_bounds__(256) void k_aggx6(const unsigned short* __restrict__ x,
    const float* __restrict__ a1, const float* __restrict__ a2,
    const int* __restrict__ row_ptr, const int* __restrict__ col_src,
    unsigned short* __restrict__ aggX, int n0base, int M){
  int idx = blockIdx.x*4 + (threadIdx.x>>6);
  if(idx >= M) return;
  int n = n0base + idx;
  int l = threadIdx.x & 63;
  int e0 = row_ptr[n], e1 = row_ptr[n+1];
  float a1v[6];
  #pragma unroll
  for(int h=0;h<6;h++) a1v[h] = a1[(size_t)n*8 + h];
  float acc[6][4];
  float d[6];
  #pragma unroll
  for(int h=0;h<6;h++){ d[h]=0.f; acc[h][0]=0.f; acc[h][1]=0.f; acc[h][2]=0.f; acc[h][3]=0.f; }
  int e = e0;
  for(; e + 2 <= e1; e += 2){
    int s0 = col_src[e], s1 = col_src[e+1];
    float4 alo0 = *(const float4*)(a2 + (size_t)s0*8);
    float2 ahi0 = *(const float2*)(a2 + (size_t)s0*8 + 4);
    float4 alo1 = *(const float4*)(a2 + (size_t)s1*8);
    float2 ahi1 = *(const float2*)(a2 + (size_t)s1*8 + 4);
    uint2 rv0 = *(const uint2*)(x + (size_t)s0*256 + l*4);
    uint2 rv1 = *(const uint2*)(x + (size_t)s1*256 + l*4);
    float ex0[6], ex1[6];
    ex0[0] = __expf(lrelu(a1v[0] + alo0.x));
    ex0[1] = __expf(lrelu(a1v[1] + alo0.y));
    ex0[2] = __expf(lrelu(a1v[2] + alo0.z));
    ex0[3] = __expf(lrelu(a1v[3] + alo0.w));
    ex0[4] = __expf(lrelu(a1v[4] + ahi0.x));
    ex0[5] = __expf(lrelu(a1v[5] + ahi0.y));
    ex1[0] = __expf(lrelu(a1v[0] + alo1.x));
    ex1[1] = __expf(lrelu(a1v[1] + alo1.y));
    ex1[2] = __expf(lrelu(a1v[2] + alo1.z));
    ex1[3] = __expf(lrelu(a1v[3] + alo1.w));
    ex1[4] = __expf(lrelu(a1v[4] + ahi1.x));
    ex1[5] = __expf(lrelu(a1v[5] + ahi1.y));
    float c00 = lo16(rv0.x), c01 = hi16(rv0.x), c02 = lo16(rv0.y), c03 = hi16(rv0.y);
    float c10 = lo16(rv1.x), c11 = hi16(rv1.x), c12 = lo16(rv1.y), c13 = hi16(rv1.y);
    #pragma unroll
    for(int h=0;h<6;h++){
      d[h] += ex0[h] + ex1[h];
      acc[h][0] += ex0[h]*c00 + ex1[h]*c10;
      acc[h][1] += ex0[h]*c01 + ex1[h]*c11;
      acc[h][2] += ex0[h]*c02 + ex1[h]*c12;
      acc[h][3] += ex0[h]*c03 + ex1[h]*c13;
    }
  }
  for(; e < e1; ++e){
    int s = col_src[e];
    float4 alo = *(const float4*)(a2 + (size_t)s*8);
    float2 ahi = *(const float2*)(a2 + (size_t)s*8 + 4);
    uint2 rv = *(const uint2*)(x + (size_t)s*256 + l*4);
    float ex[6];
    ex[0] = __expf(lrelu(a1v[0] + alo.x));
    ex[1] = __expf(lrelu(a1v[1] + alo.y));
    ex[2] = __expf(lrelu(a1v[2] + alo.z));
    ex[3] = __expf(lrelu(a1v[3] + alo.w));
    ex[4] = __expf(lrelu(a1v[4] + ahi.x));
    ex[5] = __expf(lrelu(a1v[5] + ahi.y));
    float c0 = lo16(rv.x), c1 = hi16(rv.x), c2 = lo16(rv.y), c3 = hi16(rv.y);
    #pragma unroll
    for(int h=0;h<6;h++){
      d[h] += ex[h];
      acc[h][0] += ex[h]*c0;
      acc[h][1] += ex[h]*c1;
      acc[h][2] += ex[h]*c2;
      acc[h][3] += ex[h]*c3;
    }
  }
  bool deg = e1 > e0;
  #pragma unroll
  for(int h=0;h<6;h++){
    float inv = deg ? 1.0f/d[h] : 0.0f;
    uint2 o;
    o.x = pack2(acc[h][0]*inv, acc[h][1]*inv);
    o.y = pack2(acc[h][2]*inv, acc[h][3]*inv);
    *(uint2*)(aggX + (size_t)idx*1536 + h*256 + l*4) = o;
  }
}

// ---------------- host ----------------
extern "C" void kernel_launch(void* const* d_in, const int* in_sizes, int n_in,
                              void* d_out, int out_size, void* d_ws, size_t ws_size,
                              hipStream_t stream){
  const float* features = (const float*)d_in[0];
  const int*   src      = (const int*)d_in[1];
  const int*   dst      = (const int*)d_in[2];
  const float* W0  = (const float*)d_in[3];
  const float* al0 = (const float*)d_in[4];
  const float* ar0 = (const float*)d_in[5];
  const float* W1  = (const float*)d_in[6];
  const float* al1 = (const float*)d_in[7];
  const float* ar1 = (const float*)d_in[8];
  const float* R1  = (const float*)d_in[9];
  const float* Wf  = (const float*)d_in[10];
  const float* alf = (const float*)d_in[11];
  const float* arf = (const float*)d_in[12];
  const float* Rf  = (const float*)d_in[13];
  float* out = (float*)d_out;
  (void)in_sizes; (void)n_in; (void)out_size;

  char* ws = (char*)d_ws;
  size_t off = 0;
  auto take = [&](size_t bytes) -> void* {
    void* p = ws + off;
    off += (bytes + 255) & ~(size_t)255;
    return p;
  };
  const int CH = 25000;
  int* row_ptr = (int*)take((NN + 1) * sizeof(int));
  int* cur     = (int*)take(NN * sizeof(int));
  int* col_src = (int*)take(NE * sizeof(int));
  int* bsum    = (int*)take(256 * sizeof(int));
  int* boff    = (int*)take(257 * sizeof(int));
  float* a1A = (float*)take((size_t)NN * 8 * sizeof(float));
  float* a2A = (float*)take((size_t)NN * 8 * sizeof(float));
  float* a1B = (float*)take((size_t)NN * 8 * sizeof(float));
  float* a2B = (float*)take((size_t)NN * 8 * sizeof(float));
  unsigned short* ftres  = (unsigned short*)take((size_t)NN * 512 * 2);  // 51.2 MB
  unsigned short* feat16 = (unsigned short*)take((size_t)NN * 256 * 2);
  unsigned short* hA16   = (unsigned short*)take((size_t)NN * 256 * 2);
  unsigned short* hB16   = (unsigned short*)take((size_t)NN * 256 * 2);
  unsigned short* aggX   = (unsigned short*)take((size_t)CH * 1536 * 2); // 76.8 MB
  unsigned short* w016  = (unsigned short*)take(65536 * 2);
  unsigned short* w1r1  = (unsigned short*)take(131072 * 2);
  unsigned short* wf16  = (unsigned short*)take(185856 * 2);
  unsigned short* rf16  = (unsigned short*)take(185856 * 2);
  float* fl0 = (float*)take(4*256*sizeof(float));
  float* fr0 = (float*)take(4*256*sizeof(float));
  float* fl1 = (float*)take(4*256*sizeof(float));
  float* fr1 = (float*)take(4*256*sizeof(float));
  float* flF = (float*)take(6*256*sizeof(float));
  float* frF = (float*)take(6*256*sizeof(float));
  size_t need = off;

  if(ws_size < need){
    k_diag<<<1, 1, 0, stream>>>(out, 100.0f + (float)((double)ws_size / 1073741824.0));
    return;
  }

  // bf16 partials [6][CH][128] (38.4 MB) alias dead ftres region in the final phase
  unsigned short* partialF = ftres;

  // CSR build
  hipMemsetAsync(cur, 0, NN * sizeof(int), stream);
  k_count<<<(NE + 255)/256, 256, 0, stream>>>(dst, cur, NE);
  k_scanA<<<NB, 256, 0, stream>>>(cur, row_ptr, bsum, NN);
  k_scanB<<<1, 256, 0, stream>>>(bsum, boff, NB);
  k_scanC<<<NB, 256, 0, stream>>>(row_ptr, boff, NN, NB);
  hipMemsetAsync(cur, 0, NN * sizeof(int), stream);
  k_scatter<<<(NE + 255)/256, 256, 0, stream>>>(src, dst, row_ptr, cur, col_src, NE);

  // converts + folds
  k_cvt<<<(NN*256/4 + 255)/256, 256, 0, stream>>>(features, feat16, NN*256);
  k_cvt3<<<dim3(64, 3), 256, 0, stream>>>(W0, W1, R1, w016, w1r1, w1r1 + 65536, 65536);
  k_cvt2<<<dim3(182, 2), 256, 0, stream>>>(Wf, Rf, wf16, rf16, 185856);
  k_foldAll<<<14, 256, 0, stream>>>(W0, al0, ar0, W1, al1, ar1, Wf, alf, arf,
                                    fl0, fr0, fl1, fr1, flF, frF);

  int gm = (NN + 127) / 128;   // 391
  int gagg = (NN + 3) / 4;     // 12500

  // Layer 0: a12(A) -> GEMM -> agg (reads A, writes hA + next a12 into B)
  k_a12dot<4,4><<<gagg, 256, 0, stream>>>(feat16, fl0, fr0, a1A, a2A);
  k_gemm16<<<dim3(gm, 2), 256, 0, stream>>>(feat16, w016, ftres, NN, 256, 256);
  k_agg4<false,4,4><<<gagg, 256, 0, stream>>>(ftres, 256, a1A, a2A, row_ptr, col_src,
      nullptr, 0, hA16, fl1, fr1, a1B, a2B);

  // Layer 1: fused [W1;R1] GEMM (stride-512) -> agg (reads B, writes hB + final a12 into A)
  k_gemm16<<<dim3(gm, 4), 256, 0, stream>>>(hA16, w1r1, ftres, NN, 512, 512);
  k_agg4<true,6,8><<<gagg, 256, 0, stream>>>(ftres, 512, a1B, a2B, row_ptr, col_src,
      ftres + 256, 512, hB16, flF, frF, a1A, a2A);

  // Final layer (reads a1A/a2A with stride 8)
  for(int c = 0; c < 2; c++){
    int n0 = c*CH;
    k_aggx6<<<(CH + 3)/4, 256, 0, stream>>>(hB16, a1A, a2A, row_ptr, col_src, aggX, n0, CH);
    k_gemmFh<<<dim3((CH + 127)/128, 6), 256, 0, stream>>>(aggX, hB16 + (size_t)n0*256, wf16, rf16, partialF, CH);
    k_reduce6<<<(CH*128 + 255)/256, 256, 0, stream>>>(partialF, out, n0, CH);
  }
}